// Round 9
// baseline (214.484 us; speedup 1.0000x reference)
//
#include <hip/hip_runtime.h>

typedef __bf16 bf16_t;
typedef __bf16 bf16x8 __attribute__((ext_vector_type(8)));
typedef __bf16 bf16x4 __attribute__((ext_vector_type(4)));
typedef float f32x4 __attribute__((ext_vector_type(4)));
typedef float f32x16 __attribute__((ext_vector_type(16)));
typedef unsigned int u32;

#define GLB_AS(p) ((const __attribute__((address_space(1))) unsigned int*)(p))
#define LDS_AS(p) ((__attribute__((address_space(3))) unsigned int*)(p))

// ---------------- fp32 -> bf16 convert (vectorized), optional scale ----------------
__global__ void cvt_bf16_kernel(const float* __restrict__ in, bf16_t* __restrict__ out, int n, float scale)
{
    int i = (blockIdx.x * blockDim.x + threadIdx.x) * 4;
    if (i >= n) return;
    float4 v = *(const float4*)(in + i);
    bf16x4 o;
    o[0] = (bf16_t)(v.x * scale); o[1] = (bf16_t)(v.y * scale);
    o[2] = (bf16_t)(v.z * scale); o[3] = (bf16_t)(v.w * scale);
    *(bf16x4*)(out + i) = o;
}

// ---------------- weight transpose: in f32 [R][C] -> out bf16 [C][R] ----------------
__global__ void wtrans_kernel(const float* __restrict__ in, bf16_t* __restrict__ out, int R, int C)
{
    __shared__ float tile[32][33];
    const int tid = threadIdx.x;
    const int r0 = blockIdx.y * 32, c0 = blockIdx.x * 32;
#pragma unroll
    for (int j = 0; j < 4; j++) {
        int r = j * 8 + (tid >> 5), c = tid & 31;
        tile[r][c] = in[(size_t)(r0 + r) * C + c0 + c];
    }
    __syncthreads();
#pragma unroll
    for (int j = 0; j < 4; j++) {
        int c = j * 8 + (tid >> 5), r = tid & 31;
        out[(size_t)(c0 + c) * R + r0 + r] = (bf16_t)tile[r][c];
    }
}

// ---------------- V transpose: QKV cols 1024..1535 -> Vt[bh][64][2048] ----------------
__global__ void vtrans_kernel(const bf16_t* __restrict__ qkv, bf16_t* __restrict__ vt)
{
    __shared__ bf16_t t[64][68];
    const int tid = threadIdx.x;
    const int lk0 = blockIdx.x * 64;
    const int bh = blockIdx.y, b = bh >> 3, h = bh & 7;
#pragma unroll
    for (int j = 0; j < 16; j++) {
        int e = j * 256 + tid;
        int lk_i = e >> 6, d = e & 63;
        t[lk_i][d] = qkv[(size_t)(b * 2048 + lk0 + lk_i) * 1536 + 1024 + h * 64 + d];
    }
    __syncthreads();
#pragma unroll
    for (int j = 0; j < 16; j++) {
        int e = j * 256 + tid;
        int d_i = e >> 6, lk = e & 63;
        vt[((size_t)bh * 64 + d_i) * 2048 + lk0 + lk] = t[lk][d_i];
    }
}

// ---------------- GEMM: C[M][N] = A[M][K] @ Bt[N][K]^T ----------------
template<int BM, bool SPLITA, bool BIAS, bool RELU, bool OUTBF16>
__global__ __launch_bounds__(256)
void gemm_kernel(const bf16_t* __restrict__ A0, const bf16_t* __restrict__ A1, int nsplit,
                 const bf16_t* __restrict__ Bt, const float* __restrict__ bias,
                 void* __restrict__ Cout, int K, int ldC)
{
    constexpr int FR = BM / 32;
    __shared__ __align__(16) bf16_t As[BM * 32];
    __shared__ __align__(16) bf16_t Bs[128 * 32];
    const int bm = blockIdx.x, bn = blockIdx.y;
    const bf16_t* A = (!SPLITA || bn < nsplit) ? A0 : A1;
    const int tid = threadIdx.x;
    const int lane = tid & 63;
    const int wid = tid >> 6;
    const int wr = wid >> 1, wc = wid & 1;

    f32x4 acc[FR][4] = {};

    const int cb = wid * 2;
    const int lbB0 = cb * 1024 + lane * 16;
    const int rowB0 = lbB0 >> 6, colB0 = (lbB0 & 63) >> 1;
    const int rowB1 = (lbB0 + 1024) >> 6, colB1 = ((lbB0 + 1024) & 63) >> 1;
    const int lbA0 = (BM == 128 ? cb * 1024 : wid * 1024) + lane * 16;
    const int rowA0 = lbA0 >> 6, colA0 = (lbA0 & 63) >> 1;
    const int rowA1 = (lbA0 + 1024) >> 6, colA1 = ((lbA0 + 1024) & 63) >> 1;

    const bf16_t* Abase = A + (size_t)(bm * BM) * K;
    const bf16_t* Bbase = Bt + (size_t)(bn * 128) * K;

    for (int k0 = 0; k0 < K; k0 += 32) {
        if constexpr (BM == 128) {
            __builtin_amdgcn_global_load_lds(GLB_AS(Abase + (size_t)rowA0 * K + k0 + colA0), LDS_AS(As + cb * 512), 16, 0, 0);
            __builtin_amdgcn_global_load_lds(GLB_AS(Abase + (size_t)rowA1 * K + k0 + colA1), LDS_AS(As + cb * 512 + 512), 16, 0, 0);
        } else {
            __builtin_amdgcn_global_load_lds(GLB_AS(Abase + (size_t)rowA0 * K + k0 + colA0), LDS_AS(As + wid * 512), 16, 0, 0);
        }
        __builtin_amdgcn_global_load_lds(GLB_AS(Bbase + (size_t)rowB0 * K + k0 + colB0), LDS_AS(Bs + cb * 512), 16, 0, 0);
        __builtin_amdgcn_global_load_lds(GLB_AS(Bbase + (size_t)rowB1 * K + k0 + colB1), LDS_AS(Bs + cb * 512 + 512), 16, 0, 0);
        __syncthreads();
        bf16x8 af[FR], bfr[4];
#pragma unroll
        for (int f = 0; f < FR; f++)
            af[f] = *(const bf16x8*)&As[(wr * (BM / 2) + f * 16 + (lane & 15)) * 32 + (lane >> 4) * 8];
#pragma unroll
        for (int f = 0; f < 4; f++)
            bfr[f] = *(const bf16x8*)&Bs[(wc * 64 + f * 16 + (lane & 15)) * 32 + (lane >> 4) * 8];
#pragma unroll
        for (int fr = 0; fr < FR; fr++)
#pragma unroll
            for (int fc = 0; fc < 4; fc++)
                acc[fr][fc] = __builtin_amdgcn_mfma_f32_16x16x32_bf16(af[fr], bfr[fc], acc[fr][fc], 0, 0, 0);
        __syncthreads();
    }

    const int rg = (lane >> 4) * 4, cl = lane & 15;
#pragma unroll
    for (int fc = 0; fc < 4; fc++) {
        const int col = bn * 128 + wc * 64 + fc * 16 + cl;
        float bv = 0.f;
        if (BIAS) bv = bias[col];
#pragma unroll
        for (int fr = 0; fr < FR; fr++) {
#pragma unroll
            for (int r = 0; r < 4; r++) {
                int rowg = bm * BM + wr * (BM / 2) + fr * 16 + rg + r;
                float v = acc[fr][fc][r] + bv;
                if (RELU) v = fmaxf(v, 0.f);
                if (OUTBF16) ((bf16_t*)Cout)[(size_t)rowg * ldC + col] = (bf16_t)v;
                else         ((float*)Cout)[(size_t)rowg * ldC + col] = v;
            }
        }
    }
}

// ---------------- flash attention: swapped-QK^T 32x32, LDS-staged K/V, in-block kv-split ----------------
union BU { bf16x8 v; u32 d[4]; };

static __device__ __forceinline__ u32 pkbf(float a, float b)
{
    union { bf16_t h[2]; u32 w; } u;
    u.h[0] = (bf16_t)a; u.h[1] = (bf16_t)b;
    return u.w;
}

#define KLD 68   // K tile LDS row stride (64 + 4): read banks 2-way (free)
#define VLD 44   // V tile LDS row stride (32 + 12): read banks 2-way (free)

// grid (64 qblocks, 16 bh); block = 4 waves over the SAME 32 q-rows; wave w covers kv
// quarter [w*512, w*512+512), KVBLK=32. Per iter (wave-private, barrier-free):
//   1) coalesced global loads of NEXT K/V tile into regs (T14 issue-early)
//   2) ds_read_b128 fragments of current tile from padded LDS
//   3) R8's in-register softmax (P=mfma(K,Q), 15-fmax tree + 1 shfl, exp2 domain,
//      T13 defer-rescale, pack+8 shfl -> PV B-frag, O^T=mfma(Vt,P))
//   4) ds_write next tile (same-wave DS order makes this safe single-buffered)
// Epilogue: per-wave normalized bf16 O^T -> LDS (reusing K region) + (m,l); one
// __syncthreads; cross-wave weighted combine -> coalesced f32 O write. No global
// partials, no combine kernel.
__global__ __launch_bounds__(256)
void flash_kernel(const bf16_t* __restrict__ QKV, const bf16_t* __restrict__ Vt,
                  float* __restrict__ O)
{
    const int tid = threadIdx.x, lane = tid & 63, wid = tid >> 6;
    const int bh = blockIdx.y, b = bh >> 3, h = bh & 7;
    const int qbase = blockIdx.x * 32;
    const int l31 = lane & 31, hi = lane >> 5;

    __shared__ __align__(16) bf16_t Kst[4][32 * KLD];
    __shared__ __align__(16) bf16_t Vst[4][64 * VLD];
    __shared__ float2 mlsh[4][32];
    bf16_t* kw = &Kst[wid][0];
    bf16_t* vw = &Vst[wid][0];

    const bf16_t* Qp = QKV + (size_t)(b * 2048 + qbase + l31) * 1536 + h * 64 + hi * 8;
    const bf16_t* Kbase = QKV + (size_t)(b * 2048) * 1536 + 512 + h * 64;
    const bf16_t* Vbase = Vt + (size_t)bh * 64 * 2048;

    // staging lane geometry (coalesced: 16B per lane)
    const int krr = lane >> 3, kcc = (lane & 7) * 8;   // K: 8 lanes/row
    const int vrr = lane >> 2, vcc = (lane & 3) * 8;   // V: 4 lanes/row

    bf16x8 qf[4];
#pragma unroll
    for (int t = 0; t < 4; t++)
        qf[t] = *(const bf16x8*)(Qp + t * 16);

    f32x16 acc0 = {}, acc1 = {};
    float mrun = -1e30f, lsum = 0.f;

    const int kv0 = wid * 512, kvend = kv0 + 512;
    bf16x8 kreg[4], vreg[4];

    // prologue: stage tile 0
#pragma unroll
    for (int j = 0; j < 4; j++)
        kreg[j] = *(const bf16x8*)(Kbase + (size_t)(kv0 + j * 8 + krr) * 1536 + kcc);
#pragma unroll
    for (int j = 0; j < 4; j++)
        vreg[j] = *(const bf16x8*)(Vbase + (size_t)(j * 16 + vrr) * 2048 + kv0 + vcc);
#pragma unroll
    for (int j = 0; j < 4; j++)
        *(bf16x8*)&kw[(j * 8 + krr) * KLD + kcc] = kreg[j];
#pragma unroll
    for (int j = 0; j < 4; j++)
        *(bf16x8*)&vw[(j * 16 + vrr) * VLD + vcc] = vreg[j];

#pragma unroll 2
    for (int kt = kv0; kt < kvend; kt += 32) {
        const bool haveNext = (kt + 32 < kvend);
        // 1) issue next tile's coalesced global loads
        if (haveNext) {
            const int kn = kt + 32;
#pragma unroll
            for (int j = 0; j < 4; j++)
                kreg[j] = *(const bf16x8*)(Kbase + (size_t)(kn + j * 8 + krr) * 1536 + kcc);
#pragma unroll
            for (int j = 0; j < 4; j++)
                vreg[j] = *(const bf16x8*)(Vbase + (size_t)(j * 16 + vrr) * 2048 + kn + vcc);
        }

        // 2) fragments of current tile from LDS
        bf16x8 kf[4];
#pragma unroll
        for (int t = 0; t < 4; t++)
            kf[t] = *(const bf16x8*)&kw[l31 * KLD + hi * 8 + t * 16];
        bf16x8 vf00 = *(const bf16x8*)&vw[l31 * VLD + hi * 8];
        bf16x8 vf01 = *(const bf16x8*)&vw[l31 * VLD + 16 + hi * 8];
        bf16x8 vf10 = *(const bf16x8*)&vw[(32 + l31) * VLD + hi * 8];
        bf16x8 vf11 = *(const bf16x8*)&vw[(32 + l31) * VLD + 16 + hi * 8];

        // 3) QK^T swapped: p[reg=kv][lane=q]
        f32x16 p = {};
        __builtin_amdgcn_s_setprio(1);
        p = __builtin_amdgcn_mfma_f32_32x32x16_bf16(kf[0], qf[0], p, 0, 0, 0);
        p = __builtin_amdgcn_mfma_f32_32x32x16_bf16(kf[1], qf[1], p, 0, 0, 0);
        p = __builtin_amdgcn_mfma_f32_32x32x16_bf16(kf[2], qf[2], p, 0, 0, 0);
        p = __builtin_amdgcn_mfma_f32_32x32x16_bf16(kf[3], qf[3], p, 0, 0, 0);
        __builtin_amdgcn_s_setprio(0);

        float x0 = fmaxf(p[0], p[8]),  x1 = fmaxf(p[1], p[9]);
        float x2 = fmaxf(p[2], p[10]), x3 = fmaxf(p[3], p[11]);
        float x4 = fmaxf(p[4], p[12]), x5 = fmaxf(p[5], p[13]);
        float x6 = fmaxf(p[6], p[14]), x7 = fmaxf(p[7], p[15]);
        x0 = fmaxf(x0, x4); x1 = fmaxf(x1, x5); x2 = fmaxf(x2, x6); x3 = fmaxf(x3, x7);
        float cm = fmaxf(fmaxf(x0, x1), fmaxf(x2, x3));
        cm = fmaxf(cm, __shfl_xor(cm, 32));

        if (__any(cm > mrun + 12.0f)) {
            float mnew = fmaxf(mrun, cm);
            float fac = __builtin_amdgcn_exp2f(mrun - mnew);
#pragma unroll
            for (int i = 0; i < 16; i++) { acc0[i] *= fac; acc1[i] *= fac; }
            lsum *= fac;
            mrun = mnew;
        }

        float e[16];
#pragma unroll
        for (int i = 0; i < 16; i++) e[i] = __builtin_amdgcn_exp2f(p[i] - mrun);

        float s0 = (e[0] + e[8]) + (e[1] + e[9]);
        float s1 = (e[2] + e[10]) + (e[3] + e[11]);
        float s2 = (e[4] + e[12]) + (e[5] + e[13]);
        float s3 = (e[6] + e[14]) + (e[7] + e[15]);
        float ts = (s0 + s1) + (s2 + s3);
        ts += __shfl_xor(ts, 32);
        lsum += ts;

        u32 pk0 = pkbf(e[0], e[1]),   pk1 = pkbf(e[2], e[3]);
        u32 pk2 = pkbf(e[4], e[5]),   pk3 = pkbf(e[6], e[7]);
        u32 pk4 = pkbf(e[8], e[9]),   pk5 = pkbf(e[10], e[11]);
        u32 pk6 = pkbf(e[12], e[13]), pk7 = pkbf(e[14], e[15]);
        u32 s0w = __shfl_xor(pk0, 32), s1w = __shfl_xor(pk1, 32);
        u32 s2w = __shfl_xor(pk2, 32), s3w = __shfl_xor(pk3, 32);
        u32 s4w = __shfl_xor(pk4, 32), s5w = __shfl_xor(pk5, 32);
        u32 s6w = __shfl_xor(pk6, 32), s7w = __shfl_xor(pk7, 32);

        BU b0, b1;
        b0.d[0] = hi ? s2w : pk0;  b0.d[1] = hi ? s3w : pk1;
        b0.d[2] = hi ? pk2 : s0w;  b0.d[3] = hi ? pk3 : s1w;
        b1.d[0] = hi ? s6w : pk4;  b1.d[1] = hi ? s7w : pk5;
        b1.d[2] = hi ? pk6 : s4w;  b1.d[3] = hi ? pk7 : s5w;

        __builtin_amdgcn_s_setprio(1);
        acc0 = __builtin_amdgcn_mfma_f32_32x32x16_bf16(vf00, b0.v, acc0, 0, 0, 0);
        acc0 = __builtin_amdgcn_mfma_f32_32x32x16_bf16(vf01, b1.v, acc0, 0, 0, 0);
        acc1 = __builtin_amdgcn_mfma_f32_32x32x16_bf16(vf10, b0.v, acc1, 0, 0, 0);
        acc1 = __builtin_amdgcn_mfma_f32_32x32x16_bf16(vf11, b1.v, acc1, 0, 0, 0);
        __builtin_amdgcn_s_setprio(0);

        // 4) commit next tile (same-wave DS order: after this iter's frag reads)
        if (haveNext) {
#pragma unroll
            for (int j = 0; j < 4; j++)
                *(bf16x8*)&kw[(j * 8 + krr) * KLD + kcc] = kreg[j];
#pragma unroll
            for (int j = 0; j < 4; j++)
                *(bf16x8*)&vw[(j * 16 + vrr) * VLD + vcc] = vreg[j];
        }
    }

    // epilogue: per-wave normalized partial O^T -> LDS (reuse K region) + (m,l)
    float inv = 1.f / lsum;
    bf16_t* tw = kw;  // 32*68 elems: exactly the K staging region
#pragma unroll
    for (int r = 0; r < 16; r++) {
        int drow = (r & 3) + 8 * (r >> 2) + 4 * hi;
        tw[l31 * KLD + drow]      = (bf16_t)(acc0[r] * inv);
        tw[l31 * KLD + 32 + drow] = (bf16_t)(acc1[r] * inv);
    }
    if (lane < 32) mlsh[wid][l31] = make_float2(mrun, lsum);
    __syncthreads();

    // cross-wave combine: thread -> (q = tid>>3, d0 = (tid&7)*8), 8 outputs
    {
        const int q = tid >> 3, d0 = (tid & 7) * 8;
        float2 m0 = mlsh[0][q], m1 = mlsh[1][q], m2 = mlsh[2][q], m3 = mlsh[3][q];
        float M = fmaxf(fmaxf(m0.x, m1.x), fmaxf(m2.x, m3.x));
        float w0 = m0.y * __builtin_amdgcn_exp2f(m0.x - M);
        float w1 = m1.y * __builtin_amdgcn_exp2f(m1.x - M);
        float w2 = m2.y * __builtin_amdgcn_exp2f(m2.x - M);
        float w3 = m3.y * __builtin_amdgcn_exp2f(m3.x - M);
        float winv = 1.f / (w0 + w1 + w2 + w3);
        bf16x8 p0 = *(const bf16x8*)&Kst[0][q * KLD + d0];
        bf16x8 p1 = *(const bf16x8*)&Kst[1][q * KLD + d0];
        bf16x8 p2 = *(const bf16x8*)&Kst[2][q * KLD + d0];
        bf16x8 p3 = *(const bf16x8*)&Kst[3][q * KLD + d0];
        float4 o1, o2;
        float* op = &o1.x;
#pragma unroll
        for (int k = 0; k < 8; k++) {
            float v = (w0 * (float)p0[k] + w1 * (float)p1[k]
                     + w2 * (float)p2[k] + w3 * (float)p3[k]) * winv;
            if (k < 4) (&o1.x)[k] = v; else (&o2.x)[k - 4] = v;
        }
        (void)op;
        float* dst = O + (size_t)(b * 2048 + qbase + q) * 512 + h * 64 + d0;
        *(float4*)dst = o1;
        *(float4*)(dst + 4) = o2;
    }
}

// ---------------- fused residual-add + LayerNorm (D=512) ----------------
template<bool RESBF>
__global__ __launch_bounds__(128)
void add_ln_kernel(const float* __restrict__ a, const void* __restrict__ res,
                   const float* __restrict__ g, const float* __restrict__ bta,
                   float* outf, bf16_t* outb)
{
    const int row = blockIdx.x, tid = threadIdx.x;
    const float4* a4 = (const float4*)(a + (size_t)row * 512);
    float4 av = a4[tid];
    float r0, r1, r2, r3;
    if (RESBF) {
        bf16x4 rv = ((const bf16x4*)res)[row * 128 + tid];
        r0 = (float)rv[0]; r1 = (float)rv[1]; r2 = (float)rv[2]; r3 = (float)rv[3];
    } else {
        float4 rv = ((const float4*)res)[row * 128 + tid];
        r0 = rv.x; r1 = rv.y; r2 = rv.z; r3 = rv.w;
    }
    float x0 = av.x + r0, x1 = av.y + r1, x2 = av.z + r2, x3 = av.w + r3;
    float s = x0 + x1 + x2 + x3;
    float sq = x0 * x0 + x1 * x1 + x2 * x2 + x3 * x3;
#pragma unroll
    for (int d = 1; d < 64; d <<= 1) { s += __shfl_xor(s, d); sq += __shfl_xor(sq, d); }
    __shared__ float red[2][2];
    const int wid = tid >> 6;
    if ((tid & 63) == 0) { red[wid][0] = s; red[wid][1] = sq; }
    __syncthreads();
    s = red[0][0] + red[1][0];
    sq = red[0][1] + red[1][1];
    float mu = s * (1.f / 512.f);
    float var = sq * (1.f / 512.f) - mu * mu;
    float rstd = rsqrtf(var + 1e-5f);
    const float4* g4 = (const float4*)g;
    const float4* b4 = (const float4*)bta;
    float4 gv = g4[tid], bv = b4[tid];
    float4 y;
    y.x = (x0 - mu) * rstd * gv.x + bv.x;
    y.y = (x1 - mu) * rstd * gv.y + bv.y;
    y.z = (x2 - mu) * rstd * gv.z + bv.z;
    y.w = (x3 - mu) * rstd * gv.w + bv.w;
    if (outf) ((float4*)(outf + (size_t)row * 512))[tid] = y;
    if (outb) {
        bf16x4 o;
        o[0] = (bf16_t)y.x; o[1] = (bf16_t)y.y; o[2] = (bf16_t)y.z; o[3] = (bf16_t)y.w;
        *(bf16x4*)(outb + (size_t)row * 512 + tid * 4) = o;
    }
}

// ---------------- orchestration ----------------
// Workspace arena (29.5 MB high-water; lifetime-safe aliasing) — R4-proven layout:
//   0- 2 MB : W1t    (A->F)
//   2- 4 MB : W2t    (A->G)
//   4-12 MB : Xb(4-8)+Eb(8-12) (A->B); out1b at 4-8 (E->H)
//  12-24 MB : QKVb   (B->D); then Hb[0:12MB]   (F->G)
//  24-28 MB : Vtb    (C->D); then Hb[12:16MB]  (F->G)
//  28-29.5  : Wqkvt  (A->B)
// d_out (8 MB f32) doubles as O (D->E) and FF (G->H, consumed in-place by LN2).
extern "C" void kernel_launch(void* const* d_in, const int* in_sizes, int n_in,
                              void* d_out, int out_size, void* d_ws, size_t ws_size,
                              hipStream_t stream)
{
    const float* inputs = (const float*)d_in[0];
    const float* encx   = (const float*)d_in[1];
    const float* Wq     = (const float*)d_in[2];
    const float* Wk     = (const float*)d_in[3];
    const float* Wv     = (const float*)d_in[4];
    const float* ln1g   = (const float*)d_in[5];
    const float* ln1b   = (const float*)d_in[6];
    const float* W1     = (const float*)d_in[7];
    const float* b1     = (const float*)d_in[8];
    const float* W2     = (const float*)d_in[9];
    const float* b2     = (const float*)d_in[10];
    const float* ln2g   = (const float*)d_in[11];
    const float* ln2b   = (const float*)d_in[12];

    char* ws = (char*)d_ws;
    const size_t MB = 1u << 20;
    bf16_t* W1t   = (bf16_t*)(ws);
    bf16_t* W2t   = (bf16_t*)(ws + 2 * MB);
    bf16_t* Xb    = (bf16_t*)(ws + 4 * MB);
    bf16_t* out1b = (bf16_t*)(ws + 4 * MB);       // aliases Xb (dead after QKV gemm)
    bf16_t* Eb    = (bf16_t*)(ws + 8 * MB);
    bf16_t* QKVb  = (bf16_t*)(ws + 12 * MB);
    bf16_t* Hb    = (bf16_t*)(ws + 12 * MB);      // aliases QKVb+Vtb (dead after flash)
    bf16_t* Vtb   = (bf16_t*)(ws + 24 * MB);
    bf16_t* Wqkvt = (bf16_t*)(ws + 28 * MB);
    float*  Obuf  = (float*)d_out;                // O (dead after ln1)
    float*  FF    = (float*)d_out;                // FF (consumed in-place by ln2)

    // A. converts + weight transposes.  Q path folds 0.125 * log2(e) (exp2 domain).
    cvt_bf16_kernel<<<2048, 256, 0, stream>>>(inputs, Xb, 2097152, 0.125f * 1.44269504f);
    cvt_bf16_kernel<<<2048, 256, 0, stream>>>(encx, Eb, 2097152, 1.0f);
    wtrans_kernel<<<dim3(16, 16), 256, 0, stream>>>(Wq, Wqkvt,              512, 512);
    wtrans_kernel<<<dim3(16, 16), 256, 0, stream>>>(Wk, Wqkvt + 512 * 512,  512, 512);
    wtrans_kernel<<<dim3(16, 16), 256, 0, stream>>>(Wv, Wqkvt + 1024 * 512, 512, 512);
    wtrans_kernel<<<dim3(64, 16), 256, 0, stream>>>(W1, W1t, 512, 2048);
    wtrans_kernel<<<dim3(16, 64), 256, 0, stream>>>(W2, W2t, 2048, 512);
    // B. fused QKV projection: C[4096][1536]
    gemm_kernel<64, true, false, false, true><<<dim3(64, 12), 256, 0, stream>>>(
        Xb, Eb, 4, Wqkvt, nullptr, QKVb, 512, 1536);
    // C. V -> Vt[bh][64][2048]
    vtrans_kernel<<<dim3(32, 16), 256, 0, stream>>>(QKVb, Vtb);
    // D. flash attention (in-block kv-split, LDS-staged) -> O f32 directly
    flash_kernel<<<dim3(64, 16), 256, 0, stream>>>(QKVb, Vtb, Obuf);
    // E. out1 = LN(O + inputs) -> bf16 only
    add_ln_kernel<false><<<4096, 128, 0, stream>>>(Obuf, inputs, ln1g, ln1b, nullptr, out1b);
    // F. H = relu(out1 @ W1 + b1)  [4096][2048] bf16
    gemm_kernel<128, false, true, true, true><<<dim3(32, 16), 256, 0, stream>>>(
        out1b, nullptr, 0, W1t, b1, Hb, 512, 2048);
    // G. FF = H @ W2 + b2  [4096][512] f32 -> d_out
    gemm_kernel<64, false, true, false, false><<<dim3(64, 4), 256, 0, stream>>>(
        Hb, nullptr, 0, W2t, b2, FF, 2048, 512);
    // H. final = LN(FF + out1b) -> d_out (in-place, row-local)
    add_ln_kernel<true><<<4096, 128, 0, stream>>>(FF, out1b, ln2g, ln2b, (float*)d_out, nullptr);
}

// Round 10
// 171.756 us; speedup vs baseline: 1.2488x; 1.2488x over previous
//
#include <hip/hip_runtime.h>

typedef __bf16 bf16_t;
typedef __bf16 bf16x8 __attribute__((ext_vector_type(8)));
typedef __bf16 bf16x4 __attribute__((ext_vector_type(4)));
typedef float f32x4 __attribute__((ext_vector_type(4)));
typedef float f32x16 __attribute__((ext_vector_type(16)));
typedef unsigned int u32;

#define GLB_AS(p) ((const __attribute__((address_space(1))) unsigned int*)(p))
#define LDS_AS(p) ((__attribute__((address_space(3))) unsigned int*)(p))

// rows per KV-split = 16 bh * 2048 q = 32768; 4 splits of 512 kv each
#define SPLIT_ROWS 32768

// ---------------- merged fp32 -> bf16 convert: inputs (scaled) + encoder ----------------
__global__ void cvt_both_kernel(const float* __restrict__ inA, bf16_t* __restrict__ outA, float scaleA,
                                const float* __restrict__ inB, bf16_t* __restrict__ outB)
{
    const int bid = blockIdx.x;
    const float* in;
    bf16_t* out;
    float scale;
    int i;
    if (bid < 2048) { in = inA; out = outA; scale = scaleA; i = (bid * 256 + threadIdx.x) * 4; }
    else            { in = inB; out = outB; scale = 1.0f;  i = ((bid - 2048) * 256 + threadIdx.x) * 4; }
    float4 v = *(const float4*)(in + i);
    bf16x4 o;
    o[0] = (bf16_t)(v.x * scale); o[1] = (bf16_t)(v.y * scale);
    o[2] = (bf16_t)(v.z * scale); o[3] = (bf16_t)(v.w * scale);
    *(bf16x4*)(out + i) = o;
}

// ---------------- merged weight transposes: f32 [R][C] -> bf16 [C][R], 5 jobs ----------------
// jobs: 0-255 Wq, 256-511 Wk, 512-767 Wv (512x512, 16x16 tiles);
//       768-1791 W1 (512x2048, 64x16); 1792-2815 W2 (2048x512, 16x64).
__global__ void wtrans_all_kernel(const float* __restrict__ Wq, const float* __restrict__ Wk,
                                  const float* __restrict__ Wv, const float* __restrict__ W1,
                                  const float* __restrict__ W2, bf16_t* __restrict__ Wqkvt,
                                  bf16_t* __restrict__ W1t, bf16_t* __restrict__ W2t)
{
    const int j = blockIdx.x;
    const float* in;
    bf16_t* out;
    int R, C, bx, by;
    if (j < 768) {
        int k = j >> 8, l = j & 255;
        in = (k == 0) ? Wq : (k == 1) ? Wk : Wv;
        out = Wqkvt + k * 512 * 512;
        R = 512; C = 512; bx = l & 15; by = l >> 4;
    } else if (j < 1792) {
        int l = j - 768;
        in = W1; out = W1t; R = 512; C = 2048; bx = l % 64; by = l / 64;
    } else {
        int l = j - 1792;
        in = W2; out = W2t; R = 2048; C = 512; bx = l % 16; by = l / 16;
    }
    __shared__ float tile[32][33];
    const int tid = threadIdx.x;
    const int r0 = by * 32, c0 = bx * 32;
#pragma unroll
    for (int t = 0; t < 4; t++) {
        int r = t * 8 + (tid >> 5), c = tid & 31;
        tile[r][c] = in[(size_t)(r0 + r) * C + c0 + c];
    }
    __syncthreads();
#pragma unroll
    for (int t = 0; t < 4; t++) {
        int c = t * 8 + (tid >> 5), r = tid & 31;
        out[(size_t)(c0 + c) * R + r0 + r] = (bf16_t)tile[r][c];
    }
}

// ---------------- V transpose: QKV cols 1024..1535 -> Vt[bh][64][2048] ----------------
__global__ void vtrans_kernel(const bf16_t* __restrict__ qkv, bf16_t* __restrict__ vt)
{
    __shared__ bf16_t t[64][68];
    const int tid = threadIdx.x;
    const int lk0 = blockIdx.x * 64;
    const int bh = blockIdx.y, b = bh >> 3, h = bh & 7;
#pragma unroll
    for (int j = 0; j < 16; j++) {
        int e = j * 256 + tid;
        int lk_i = e >> 6, d = e & 63;
        t[lk_i][d] = qkv[(size_t)(b * 2048 + lk0 + lk_i) * 1536 + 1024 + h * 64 + d];
    }
    __syncthreads();
#pragma unroll
    for (int j = 0; j < 16; j++) {
        int e = j * 256 + tid;
        int d_i = e >> 6, lk = e & 63;
        vt[((size_t)bh * 64 + d_i) * 2048 + lk0 + lk] = t[lk][d_i];
    }
}

// ---------------- GEMM: C[M][N] = A[M][K] @ Bt[N][K]^T ----------------
template<int BM, bool SPLITA, bool BIAS, bool RELU, bool OUTBF16>
__global__ __launch_bounds__(256)
void gemm_kernel(const bf16_t* __restrict__ A0, const bf16_t* __restrict__ A1, int nsplit,
                 const bf16_t* __restrict__ Bt, const float* __restrict__ bias,
                 void* __restrict__ Cout, int K, int ldC)
{
    constexpr int FR = BM / 32;
    __shared__ __align__(16) bf16_t As[BM * 32];
    __shared__ __align__(16) bf16_t Bs[128 * 32];
    const int bm = blockIdx.x, bn = blockIdx.y;
    const bf16_t* A = (!SPLITA || bn < nsplit) ? A0 : A1;
    const int tid = threadIdx.x;
    const int lane = tid & 63;
    const int wid = tid >> 6;
    const int wr = wid >> 1, wc = wid & 1;

    f32x4 acc[FR][4] = {};

    const int cb = wid * 2;
    const int lbB0 = cb * 1024 + lane * 16;
    const int rowB0 = lbB0 >> 6, colB0 = (lbB0 & 63) >> 1;
    const int rowB1 = (lbB0 + 1024) >> 6, colB1 = ((lbB0 + 1024) & 63) >> 1;
    const int lbA0 = (BM == 128 ? cb * 1024 : wid * 1024) + lane * 16;
    const int rowA0 = lbA0 >> 6, colA0 = (lbA0 & 63) >> 1;
    const int rowA1 = (lbA0 + 1024) >> 6, colA1 = ((lbA0 + 1024) & 63) >> 1;

    const bf16_t* Abase = A + (size_t)(bm * BM) * K;
    const bf16_t* Bbase = Bt + (size_t)(bn * 128) * K;

    for (int k0 = 0; k0 < K; k0 += 32) {
        if constexpr (BM == 128) {
            __builtin_amdgcn_global_load_lds(GLB_AS(Abase + (size_t)rowA0 * K + k0 + colA0), LDS_AS(As + cb * 512), 16, 0, 0);
            __builtin_amdgcn_global_load_lds(GLB_AS(Abase + (size_t)rowA1 * K + k0 + colA1), LDS_AS(As + cb * 512 + 512), 16, 0, 0);
        } else {
            __builtin_amdgcn_global_load_lds(GLB_AS(Abase + (size_t)rowA0 * K + k0 + colA0), LDS_AS(As + wid * 512), 16, 0, 0);
        }
        __builtin_amdgcn_global_load_lds(GLB_AS(Bbase + (size_t)rowB0 * K + k0 + colB0), LDS_AS(Bs + cb * 512), 16, 0, 0);
        __builtin_amdgcn_global_load_lds(GLB_AS(Bbase + (size_t)rowB1 * K + k0 + colB1), LDS_AS(Bs + cb * 512 + 512), 16, 0, 0);
        __syncthreads();
        bf16x8 af[FR], bfr[4];
#pragma unroll
        for (int f = 0; f < FR; f++)
            af[f] = *(const bf16x8*)&As[(wr * (BM / 2) + f * 16 + (lane & 15)) * 32 + (lane >> 4) * 8];
#pragma unroll
        for (int f = 0; f < 4; f++)
            bfr[f] = *(const bf16x8*)&Bs[(wc * 64 + f * 16 + (lane & 15)) * 32 + (lane >> 4) * 8];
#pragma unroll
        for (int fr = 0; fr < FR; fr++)
#pragma unroll
            for (int fc = 0; fc < 4; fc++)
                acc[fr][fc] = __builtin_amdgcn_mfma_f32_16x16x32_bf16(af[fr], bfr[fc], acc[fr][fc], 0, 0, 0);
        __syncthreads();
    }

    const int rg = (lane >> 4) * 4, cl = lane & 15;
#pragma unroll
    for (int fc = 0; fc < 4; fc++) {
        const int col = bn * 128 + wc * 64 + fc * 16 + cl;
        float bv = 0.f;
        if (BIAS) bv = bias[col];
#pragma unroll
        for (int fr = 0; fr < FR; fr++) {
#pragma unroll
            for (int r = 0; r < 4; r++) {
                int rowg = bm * BM + wr * (BM / 2) + fr * 16 + rg + r;
                float v = acc[fr][fc][r] + bv;
                if (RELU) v = fmaxf(v, 0.f);
                if (OUTBF16) ((bf16_t*)Cout)[(size_t)rowg * ldC + col] = (bf16_t)v;
                else         ((float*)Cout)[(size_t)rowg * ldC + col] = v;
            }
        }
    }
}

// ---------------- flash attention: swapped-QK^T 32x32, in-register softmax (R8, proven) ----------------
union BU { bf16x8 v; u32 d[4]; };

static __device__ __forceinline__ u32 pkbf(float a, float b)
{
    union { bf16_t h[2]; u32 w; } u;
    u.h[0] = (bf16_t)a; u.h[1] = (bf16_t)b;
    return u.w;
}

// grid (16 qblocks, 16 bh, 4 kv-splits); 4 waves x 32 q-rows = 128 q/block; KVBLK=32.
// P = mfma(K_rows, Q_rows): P[kv on reg axis][q on lane axis] -> softmax in-register
// (15-fmax tree + 1 shfl_xor(32)); pack + 8 shfl_xor(32) -> PV B-frag; O^T = mfma(Vt, P).
// C-row map: row = (reg&3) + 8*(reg>>2) + 4*(lane>>5). Q pre-scaled 0.125*log2(e);
// m in log2 units; T13 defer-rescale. Epilogue: wave-private LDS transpose -> coalesced write.
__global__ __launch_bounds__(256)
void flash_kernel(const bf16_t* __restrict__ QKV, const bf16_t* __restrict__ Vt,
                  bf16_t* __restrict__ Op01, bf16_t* __restrict__ Op23,
                  float2* __restrict__ ml)
{
    const int tid = threadIdx.x, lane = tid & 63, wid = tid >> 6;
    const int bh = blockIdx.y, b = bh >> 3, h = bh & 7;
    const int split = blockIdx.z;
    const int qbase = blockIdx.x * 128 + wid * 32;
    const int l31 = lane & 31, hi = lane >> 5;

    __shared__ __align__(16) bf16_t tlds[4][32 * 68];
    bf16_t* tw = &tlds[wid][0];

    const bf16_t* Qp = QKV + (size_t)(b * 2048 + qbase + l31) * 1536 + h * 64 + hi * 8;
    const bf16_t* Kp = QKV + (size_t)(b * 2048) * 1536 + 512 + h * 64 + hi * 8;
    const bf16_t* Vp = Vt + ((size_t)bh * 64 + l31) * 2048 + hi * 8;

    bf16x8 qf[4];
#pragma unroll
    for (int t = 0; t < 4; t++)
        qf[t] = *(const bf16x8*)(Qp + t * 16);

    f32x16 acc0 = {}, acc1 = {};
    float mrun = -1e30f, lsum = 0.f;

    const int kv0 = split * 512;
#pragma unroll 2
    for (int kt = kv0; kt < kv0 + 512; kt += 32) {
        bf16x8 kf[4];
#pragma unroll
        for (int t = 0; t < 4; t++)
            kf[t] = *(const bf16x8*)(Kp + (size_t)(kt + l31) * 1536 + t * 16);
        bf16x8 vf00 = *(const bf16x8*)(Vp + kt);
        bf16x8 vf01 = *(const bf16x8*)(Vp + kt + 16);
        bf16x8 vf10 = *(const bf16x8*)(Vp + 32 * 2048 + kt);
        bf16x8 vf11 = *(const bf16x8*)(Vp + 32 * 2048 + kt + 16);

        f32x16 p = {};
        __builtin_amdgcn_s_setprio(1);
        p = __builtin_amdgcn_mfma_f32_32x32x16_bf16(kf[0], qf[0], p, 0, 0, 0);
        p = __builtin_amdgcn_mfma_f32_32x32x16_bf16(kf[1], qf[1], p, 0, 0, 0);
        p = __builtin_amdgcn_mfma_f32_32x32x16_bf16(kf[2], qf[2], p, 0, 0, 0);
        p = __builtin_amdgcn_mfma_f32_32x32x16_bf16(kf[3], qf[3], p, 0, 0, 0);
        __builtin_amdgcn_s_setprio(0);

        float x0 = fmaxf(p[0], p[8]),  x1 = fmaxf(p[1], p[9]);
        float x2 = fmaxf(p[2], p[10]), x3 = fmaxf(p[3], p[11]);
        float x4 = fmaxf(p[4], p[12]), x5 = fmaxf(p[5], p[13]);
        float x6 = fmaxf(p[6], p[14]), x7 = fmaxf(p[7], p[15]);
        x0 = fmaxf(x0, x4); x1 = fmaxf(x1, x5); x2 = fmaxf(x2, x6); x3 = fmaxf(x3, x7);
        float cm = fmaxf(fmaxf(x0, x1), fmaxf(x2, x3));
        cm = fmaxf(cm, __shfl_xor(cm, 32));

        if (__any(cm > mrun + 12.0f)) {
            float mnew = fmaxf(mrun, cm);
            float fac = __builtin_amdgcn_exp2f(mrun - mnew);
#pragma unroll
            for (int i = 0; i < 16; i++) { acc0[i] *= fac; acc1[i] *= fac; }
            lsum *= fac;
            mrun = mnew;
        }

        float e[16];
#pragma unroll
        for (int i = 0; i < 16; i++) e[i] = __builtin_amdgcn_exp2f(p[i] - mrun);

        float s0 = (e[0] + e[8]) + (e[1] + e[9]);
        float s1 = (e[2] + e[10]) + (e[3] + e[11]);
        float s2 = (e[4] + e[12]) + (e[5] + e[13]);
        float s3 = (e[6] + e[14]) + (e[7] + e[15]);
        float ts = (s0 + s1) + (s2 + s3);
        ts += __shfl_xor(ts, 32);
        lsum += ts;

        u32 pk0 = pkbf(e[0], e[1]),   pk1 = pkbf(e[2], e[3]);
        u32 pk2 = pkbf(e[4], e[5]),   pk3 = pkbf(e[6], e[7]);
        u32 pk4 = pkbf(e[8], e[9]),   pk5 = pkbf(e[10], e[11]);
        u32 pk6 = pkbf(e[12], e[13]), pk7 = pkbf(e[14], e[15]);
        u32 s0w = __shfl_xor(pk0, 32), s1w = __shfl_xor(pk1, 32);
        u32 s2w = __shfl_xor(pk2, 32), s3w = __shfl_xor(pk3, 32);
        u32 s4w = __shfl_xor(pk4, 32), s5w = __shfl_xor(pk5, 32);
        u32 s6w = __shfl_xor(pk6, 32), s7w = __shfl_xor(pk7, 32);

        BU b0, b1;
        b0.d[0] = hi ? s2w : pk0;  b0.d[1] = hi ? s3w : pk1;
        b0.d[2] = hi ? pk2 : s0w;  b0.d[3] = hi ? pk3 : s1w;
        b1.d[0] = hi ? s6w : pk4;  b1.d[1] = hi ? s7w : pk5;
        b1.d[2] = hi ? pk6 : s4w;  b1.d[3] = hi ? pk7 : s5w;

        __builtin_amdgcn_s_setprio(1);
        acc0 = __builtin_amdgcn_mfma_f32_32x32x16_bf16(vf00, b0.v, acc0, 0, 0, 0);
        acc0 = __builtin_amdgcn_mfma_f32_32x32x16_bf16(vf01, b1.v, acc0, 0, 0, 0);
        acc1 = __builtin_amdgcn_mfma_f32_32x32x16_bf16(vf10, b0.v, acc1, 0, 0, 0);
        acc1 = __builtin_amdgcn_mfma_f32_32x32x16_bf16(vf11, b1.v, acc1, 0, 0, 0);
        __builtin_amdgcn_s_setprio(0);
    }

    float inv = 1.f / lsum;
#pragma unroll
    for (int r = 0; r < 16; r++) {
        int drow = (r & 3) + 8 * (r >> 2) + 4 * hi;
        tw[l31 * 68 + drow]      = (bf16_t)(acc0[r] * inv);
        tw[l31 * 68 + 32 + drow] = (bf16_t)(acc1[r] * inv);
    }
    bf16_t* Op = (split < 2) ? Op01 + (size_t)split * SPLIT_ROWS * 64
                             : Op23 + (size_t)(split - 2) * SPLIT_ROWS * 64;
    const size_t rowbase = (size_t)bh * 2048 + qbase;
#pragma unroll
    for (int ps = 0; ps < 4; ps++) {
        int rr = (lane >> 3) + ps * 8;
        int cc = lane & 7;
        bf16x8 ov = *(const bf16x8*)&tw[rr * 68 + cc * 8];
        *(bf16x8*)(Op + (rowbase + rr) * 64 + cc * 8) = ov;
    }
    if (lane < 32)
        ml[(size_t)split * SPLIT_ROWS + rowbase + l31] = make_float2(mrun, lsum);
}

// ---------------- combine 4 KV-split partials -> O f32 [4096][512] ----------------
__global__ __launch_bounds__(256)
void combine_kernel(const bf16_t* __restrict__ Op01, const bf16_t* __restrict__ Op23,
                    const float2* __restrict__ ml, float* __restrict__ O)
{
    int t = blockIdx.x * 256 + threadIdx.x;
    int dim = t & 63;
    int row = t >> 6;                          // bh*2048 + qrow, < 32768
    int bh = row >> 11, qrow = row & 2047;
    float2 m0 = ml[row];
    float2 m1 = ml[SPLIT_ROWS + row];
    float2 m2 = ml[2 * SPLIT_ROWS + row];
    float2 m3 = ml[3 * SPLIT_ROWS + row];
    float M = fmaxf(fmaxf(m0.x, m1.x), fmaxf(m2.x, m3.x));
    float w0 = m0.y * __builtin_amdgcn_exp2f(m0.x - M);
    float w1 = m1.y * __builtin_amdgcn_exp2f(m1.x - M);
    float w2 = m2.y * __builtin_amdgcn_exp2f(m2.x - M);
    float w3 = m3.y * __builtin_amdgcn_exp2f(m3.x - M);
    float o = (w0 * (float)Op01[(size_t)row * 64 + dim]
             + w1 * (float)Op01[(size_t)(SPLIT_ROWS + row) * 64 + dim]
             + w2 * (float)Op23[(size_t)row * 64 + dim]
             + w3 * (float)Op23[(size_t)(SPLIT_ROWS + row) * 64 + dim]) / (w0 + w1 + w2 + w3);
    int b = bh >> 3, h = bh & 7;
    O[((size_t)(b * 2048 + qrow)) * 512 + h * 64 + dim] = o;
}

// ---------------- fused residual-add + LayerNorm (D=512) ----------------
template<bool RESBF>
__global__ __launch_bounds__(128)
void add_ln_kernel(const float* __restrict__ a, const void* __restrict__ res,
                   const float* __restrict__ g, const float* __restrict__ bta,
                   float* outf, bf16_t* outb)
{
    const int row = blockIdx.x, tid = threadIdx.x;
    const float4* a4 = (const float4*)(a + (size_t)row * 512);
    float4 av = a4[tid];
    float r0, r1, r2, r3;
    if (RESBF) {
        bf16x4 rv = ((const bf16x4*)res)[row * 128 + tid];
        r0 = (float)rv[0]; r1 = (float)rv[1]; r2 = (float)rv[2]; r3 = (float)rv[3];
    } else {
        float4 rv = ((const float4*)res)[row * 128 + tid];
        r0 = rv.x; r1 = rv.y; r2 = rv.z; r3 = rv.w;
    }
    float x0 = av.x + r0, x1 = av.y + r1, x2 = av.z + r2, x3 = av.w + r3;
    float s = x0 + x1 + x2 + x3;
    float sq = x0 * x0 + x1 * x1 + x2 * x2 + x3 * x3;
#pragma unroll
    for (int d = 1; d < 64; d <<= 1) { s += __shfl_xor(s, d); sq += __shfl_xor(sq, d); }
    __shared__ float red[2][2];
    const int wid = tid >> 6;
    if ((tid & 63) == 0) { red[wid][0] = s; red[wid][1] = sq; }
    __syncthreads();
    s = red[0][0] + red[1][0];
    sq = red[0][1] + red[1][1];
    float mu = s * (1.f / 512.f);
    float var = sq * (1.f / 512.f) - mu * mu;
    float rstd = rsqrtf(var + 1e-5f);
    const float4* g4 = (const float4*)g;
    const float4* b4 = (const float4*)bta;
    float4 gv = g4[tid], bv = b4[tid];
    float4 y;
    y.x = (x0 - mu) * rstd * gv.x + bv.x;
    y.y = (x1 - mu) * rstd * gv.y + bv.y;
    y.z = (x2 - mu) * rstd * gv.z + bv.z;
    y.w = (x3 - mu) * rstd * gv.w + bv.w;
    if (outf) ((float4*)(outf + (size_t)row * 512))[tid] = y;
    if (outb) {
        bf16x4 o;
        o[0] = (bf16_t)y.x; o[1] = (bf16_t)y.y; o[2] = (bf16_t)y.z; o[3] = (bf16_t)y.w;
        *(bf16x4*)(outb + (size_t)row * 512 + tid * 4) = o;
    }
}

// ---------------- orchestration ----------------
// Workspace arena (29.5 MB high-water; lifetime-safe aliasing) — R8 layout (verified):
//   0- 2 MB : W1t    (A->F)
//   2- 4 MB : W2t    (A->G)
//   4-12 MB : Xb(4-8)+Eb(8-12) (A->B); then Opart splits 0-1 (D->D2); then out1b at 4-8 (E->H)
//  12-24 MB : QKVb   (B->D); then O f32 at 12-20 (D2->E); then Hb 12-28 (F->G)
//  24-28 MB : Vtb    (C->D); then Hb[12:16MB]   (F->G)
//  28-29.5  : Wqkvt  (A->B); then ml 1MB (4x32768 float2) (D->D2)
// d_out: Opart splits 2-3 in first 8 MB (D->D2); then FF f32 (G->H, in-place LN2).
extern "C" void kernel_launch(void* const* d_in, const int* in_sizes, int n_in,
                              void* d_out, int out_size, void* d_ws, size_t ws_size,
                              hipStream_t stream)
{
    const float* inputs = (const float*)d_in[0];
    const float* encx   = (const float*)d_in[1];
    const float* Wq     = (const float*)d_in[2];
    const float* Wk     = (const float*)d_in[3];
    const float* Wv     = (const float*)d_in[4];
    const float* ln1g   = (const float*)d_in[5];
    const float* ln1b   = (const float*)d_in[6];
    const float* W1     = (const float*)d_in[7];
    const float* b1     = (const float*)d_in[8];
    const float* W2     = (const float*)d_in[9];
    const float* b2     = (const float*)d_in[10];
    const float* ln2g   = (const float*)d_in[11];
    const float* ln2b   = (const float*)d_in[12];

    char* ws = (char*)d_ws;
    const size_t MB = 1u << 20;
    bf16_t* W1t   = (bf16_t*)(ws);
    bf16_t* W2t   = (bf16_t*)(ws + 2 * MB);
    bf16_t* Xb    = (bf16_t*)(ws + 4 * MB);
    bf16_t* Op01  = (bf16_t*)(ws + 4 * MB);       // 8 MB, aliases Xb+Eb (dead after QKV gemm)
    bf16_t* out1b = (bf16_t*)(ws + 4 * MB);       // 4 MB, aliases Op01 (dead after combine)
    bf16_t* Eb    = (bf16_t*)(ws + 8 * MB);
    bf16_t* QKVb  = (bf16_t*)(ws + 12 * MB);
    float*  Obuf  = (float*)(ws + 12 * MB);       // 8 MB f32, aliases QKVb (dead after flash)
    bf16_t* Hb    = (bf16_t*)(ws + 12 * MB);      // 16 MB, aliases Obuf+Vtb
    bf16_t* Vtb   = (bf16_t*)(ws + 24 * MB);
    bf16_t* Wqkvt = (bf16_t*)(ws + 28 * MB);
    float2* mlbuf = (float2*)(ws + 28 * MB);      // 1 MB, aliases Wqkvt (dead after QKV gemm)
    bf16_t* Op23  = (bf16_t*)d_out;               // 8 MB, d_out unused until combine
    float*  FF    = (float*)d_out;                // FF (G->H, consumed in-place by ln2)

    // A. merged convert (Q path folds 0.125*log2(e)) + merged weight transposes
    cvt_both_kernel<<<4096, 256, 0, stream>>>(inputs, Xb, 0.125f * 1.44269504f, encx, Eb);
    wtrans_all_kernel<<<2816, 256, 0, stream>>>(Wq, Wk, Wv, W1, W2, Wqkvt, W1t, W2t);
    // B. fused QKV projection: C[4096][1536]
    gemm_kernel<64, true, false, false, true><<<dim3(64, 12), 256, 0, stream>>>(
        Xb, Eb, 4, Wqkvt, nullptr, QKVb, 512, 1536);
    // C. V -> Vt[bh][64][2048]
    vtrans_kernel<<<dim3(32, 16), 256, 0, stream>>>(QKVb, Vtb);
    // D. flash attention (kv-split 4, swapped-QK 32x32) -> bf16 partials + (m,l)
    flash_kernel<<<dim3(16, 16, 4), 256, 0, stream>>>(QKVb, Vtb, Op01, Op23, mlbuf);
    // D2. combine partials -> O f32 [4096][512] (over dead QKVb)
    combine_kernel<<<8192, 256, 0, stream>>>(Op01, Op23, mlbuf, Obuf);
    // E. out1 = LN(O + inputs) -> bf16 only
    add_ln_kernel<false><<<4096, 128, 0, stream>>>(Obuf, inputs, ln1g, ln1b, nullptr, out1b);
    // F. H = relu(out1 @ W1 + b1)  [4096][2048] bf16
    gemm_kernel<128, false, true, true, true><<<dim3(32, 16), 256, 0, stream>>>(
        out1b, nullptr, 0, W1t, b1, Hb, 512, 2048);
    // G. FF = H @ W2 + b2  [4096][512] f32 -> d_out
    gemm_kernel<64, false, true, false, false><<<dim3(64, 4), 256, 0, stream>>>(
        Hb, nullptr, 0, W2t, b2, FF, 2048, 512);
    // H. final = LN(FF + out1b) -> d_out (in-place, row-local)
    add_ln_kernel<true><<<4096, 128, 0, stream>>>(FF, out1b, ln2g, ln2b, (float*)d_out, nullptr);
}

// Round 11
// 141.337 us; speedup vs baseline: 1.5175x; 1.2152x over previous
//
#include <hip/hip_runtime.h>

typedef __bf16 bf16_t;
typedef __bf16 bf16x8 __attribute__((ext_vector_type(8)));
typedef __bf16 bf16x4 __attribute__((ext_vector_type(4)));
typedef float f32x4 __attribute__((ext_vector_type(4)));
typedef float f32x16 __attribute__((ext_vector_type(16)));
typedef unsigned int u32;

#define GLB_AS(p) ((const __attribute__((address_space(1))) unsigned int*)(p))
#define LDS_AS(p) ((__attribute__((address_space(3))) unsigned int*)(p))

// rows per KV-split = 16 bh * 2048 q = 32768; 4 splits of 512 kv each
#define SPLIT_ROWS 32768
#define KLD 68   // K tile [32 kv][64 d] row stride (pad +4): 0 conflicts (R9-measured)
#define VLD 44   // V^T tile [64 d][32 kv] row stride (pad +12): 0 conflicts (R9-measured)

// ---------------- merged fp32 -> bf16 convert: inputs (scaled) + encoder ----------------
__global__ void cvt_both_kernel(const float* __restrict__ inA, bf16_t* __restrict__ outA, float scaleA,
                                const float* __restrict__ inB, bf16_t* __restrict__ outB)
{
    const int bid = blockIdx.x;
    const float* in;
    bf16_t* out;
    float scale;
    int i;
    if (bid < 2048) { in = inA; out = outA; scale = scaleA; i = (bid * 256 + threadIdx.x) * 4; }
    else            { in = inB; out = outB; scale = 1.0f;  i = ((bid - 2048) * 256 + threadIdx.x) * 4; }
    float4 v = *(const float4*)(in + i);
    bf16x4 o;
    o[0] = (bf16_t)(v.x * scale); o[1] = (bf16_t)(v.y * scale);
    o[2] = (bf16_t)(v.z * scale); o[3] = (bf16_t)(v.w * scale);
    *(bf16x4*)(out + i) = o;
}

// ---------------- merged weight transposes: f32 [R][C] -> bf16 [C][R], 5 jobs ----------------
__global__ void wtrans_all_kernel(const float* __restrict__ Wq, const float* __restrict__ Wk,
                                  const float* __restrict__ Wv, const float* __restrict__ W1,
                                  const float* __restrict__ W2, bf16_t* __restrict__ Wqkvt,
                                  bf16_t* __restrict__ W1t, bf16_t* __restrict__ W2t)
{
    const int j = blockIdx.x;
    const float* in;
    bf16_t* out;
    int R, C, bx, by;
    if (j < 768) {
        int k = j >> 8, l = j & 255;
        in = (k == 0) ? Wq : (k == 1) ? Wk : Wv;
        out = Wqkvt + k * 512 * 512;
        R = 512; C = 512; bx = l & 15; by = l >> 4;
    } else if (j < 1792) {
        int l = j - 768;
        in = W1; out = W1t; R = 512; C = 2048; bx = l % 64; by = l / 64;
    } else {
        int l = j - 1792;
        in = W2; out = W2t; R = 2048; C = 512; bx = l % 16; by = l / 16;
    }
    __shared__ float tile[32][33];
    const int tid = threadIdx.x;
    const int r0 = by * 32, c0 = bx * 32;
#pragma unroll
    for (int t = 0; t < 4; t++) {
        int r = t * 8 + (tid >> 5), c = tid & 31;
        tile[r][c] = in[(size_t)(r0 + r) * C + c0 + c];
    }
    __syncthreads();
#pragma unroll
    for (int t = 0; t < 4; t++) {
        int c = t * 8 + (tid >> 5), r = tid & 31;
        out[(size_t)(c0 + c) * R + r0 + r] = (bf16_t)tile[r][c];
    }
}

// ---------------- V transpose: QKV cols 1024..1535 -> Vt[bh][64][2048] ----------------
__global__ void vtrans_kernel(const bf16_t* __restrict__ qkv, bf16_t* __restrict__ vt)
{
    __shared__ bf16_t t[64][68];
    const int tid = threadIdx.x;
    const int lk0 = blockIdx.x * 64;
    const int bh = blockIdx.y, b = bh >> 3, h = bh & 7;
#pragma unroll
    for (int j = 0; j < 16; j++) {
        int e = j * 256 + tid;
        int lk_i = e >> 6, d = e & 63;
        t[lk_i][d] = qkv[(size_t)(b * 2048 + lk0 + lk_i) * 1536 + 1024 + h * 64 + d];
    }
    __syncthreads();
#pragma unroll
    for (int j = 0; j < 16; j++) {
        int e = j * 256 + tid;
        int d_i = e >> 6, lk = e & 63;
        vt[((size_t)bh * 64 + d_i) * 2048 + lk0 + lk] = t[lk][d_i];
    }
}

// ---------------- GEMM: C[M][N] = A[M][K] @ Bt[N][K]^T ----------------
template<int BM, bool SPLITA, bool BIAS, bool RELU, bool OUTBF16>
__global__ __launch_bounds__(256)
void gemm_kernel(const bf16_t* __restrict__ A0, const bf16_t* __restrict__ A1, int nsplit,
                 const bf16_t* __restrict__ Bt, const float* __restrict__ bias,
                 void* __restrict__ Cout, int K, int ldC)
{
    constexpr int FR = BM / 32;
    __shared__ __align__(16) bf16_t As[BM * 32];
    __shared__ __align__(16) bf16_t Bs[128 * 32];
    const int bm = blockIdx.x, bn = blockIdx.y;
    const bf16_t* A = (!SPLITA || bn < nsplit) ? A0 : A1;
    const int tid = threadIdx.x;
    const int lane = tid & 63;
    const int wid = tid >> 6;
    const int wr = wid >> 1, wc = wid & 1;

    f32x4 acc[FR][4] = {};

    const int cb = wid * 2;
    const int lbB0 = cb * 1024 + lane * 16;
    const int rowB0 = lbB0 >> 6, colB0 = (lbB0 & 63) >> 1;
    const int rowB1 = (lbB0 + 1024) >> 6, colB1 = ((lbB0 + 1024) & 63) >> 1;
    const int lbA0 = (BM == 128 ? cb * 1024 : wid * 1024) + lane * 16;
    const int rowA0 = lbA0 >> 6, colA0 = (lbA0 & 63) >> 1;
    const int rowA1 = (lbA0 + 1024) >> 6, colA1 = ((lbA0 + 1024) & 63) >> 1;

    const bf16_t* Abase = A + (size_t)(bm * BM) * K;
    const bf16_t* Bbase = Bt + (size_t)(bn * 128) * K;

    for (int k0 = 0; k0 < K; k0 += 32) {
        if constexpr (BM == 128) {
            __builtin_amdgcn_global_load_lds(GLB_AS(Abase + (size_t)rowA0 * K + k0 + colA0), LDS_AS(As + cb * 512), 16, 0, 0);
            __builtin_amdgcn_global_load_lds(GLB_AS(Abase + (size_t)rowA1 * K + k0 + colA1), LDS_AS(As + cb * 512 + 512), 16, 0, 0);
        } else {
            __builtin_amdgcn_global_load_lds(GLB_AS(Abase + (size_t)rowA0 * K + k0 + colA0), LDS_AS(As + wid * 512), 16, 0, 0);
        }
        __builtin_amdgcn_global_load_lds(GLB_AS(Bbase + (size_t)rowB0 * K + k0 + colB0), LDS_AS(Bs + cb * 512), 16, 0, 0);
        __builtin_amdgcn_global_load_lds(GLB_AS(Bbase + (size_t)rowB1 * K + k0 + colB1), LDS_AS(Bs + cb * 512 + 512), 16, 0, 0);
        __syncthreads();
        bf16x8 af[FR], bfr[4];
#pragma unroll
        for (int f = 0; f < FR; f++)
            af[f] = *(const bf16x8*)&As[(wr * (BM / 2) + f * 16 + (lane & 15)) * 32 + (lane >> 4) * 8];
#pragma unroll
        for (int f = 0; f < 4; f++)
            bfr[f] = *(const bf16x8*)&Bs[(wc * 64 + f * 16 + (lane & 15)) * 32 + (lane >> 4) * 8];
#pragma unroll
        for (int fr = 0; fr < FR; fr++)
#pragma unroll
            for (int fc = 0; fc < 4; fc++)
                acc[fr][fc] = __builtin_amdgcn_mfma_f32_16x16x32_bf16(af[fr], bfr[fc], acc[fr][fc], 0, 0, 0);
        __syncthreads();
    }

    const int rg = (lane >> 4) * 4, cl = lane & 15;
#pragma unroll
    for (int fc = 0; fc < 4; fc++) {
        const int col = bn * 128 + wc * 64 + fc * 16 + cl;
        float bv = 0.f;
        if (BIAS) bv = bias[col];
#pragma unroll
        for (int fr = 0; fr < FR; fr++) {
#pragma unroll
            for (int r = 0; r < 4; r++) {
                int rowg = bm * BM + wr * (BM / 2) + fr * 16 + rg + r;
                float v = acc[fr][fc][r] + bv;
                if (RELU) v = fmaxf(v, 0.f);
                if (OUTBF16) ((bf16_t*)Cout)[(size_t)rowg * ldC + col] = (bf16_t)v;
                else         ((float*)Cout)[(size_t)rowg * ldC + col] = v;
            }
        }
    }
}

// ---------------- flash attention: swapped-QK^T 32x32, block-shared double-buffered LDS K/V ----------------
union BU { bf16x8 v; u32 d[4]; };

static __device__ __forceinline__ u32 pkbf(float a, float b)
{
    union { bf16_t h[2]; u32 w; } u;
    u.h[0] = (bf16_t)a; u.h[1] = (bf16_t)b;
    return u.w;
}

// grid (16 qblocks, 16 bh, 4 kv-splits); 4 waves x 32 q-rows = 128 q/block; KVBLK=32.
// All 4 waves share one K tile [32 kv][64 d] + one V^T tile [64 d][32 kv] per iter,
// staged cooperatively (256 thr x 2x16B coalesced) into padded LDS (KLD/VLD: 0-conflict,
// R9-measured). Double-buffered, one __syncthreads/iter; next tile's global loads issue
// at loop top (T14) and commit via ds_write after compute. Softmax = R8/R10 in-register
// (P=mfma(K,Q), 15-fmax tree + 1 shfl_xor(32), exp2 domain, T13 defer-rescale,
// pack + 8 shfl -> PV B-frag, O^T = mfma(Vt,P)). C-row map: (reg&3)+8*(reg>>2)+4*(lane>>5).
__global__ __launch_bounds__(256)
void flash_kernel(const bf16_t* __restrict__ QKV, const bf16_t* __restrict__ Vt,
                  bf16_t* __restrict__ Op01, bf16_t* __restrict__ Op23,
                  float2* __restrict__ ml)
{
    const int tid = threadIdx.x, lane = tid & 63, wid = tid >> 6;
    const int bh = blockIdx.y, b = bh >> 3, h = bh & 7;
    const int split = blockIdx.z;
    const int qbase = blockIdx.x * 128 + wid * 32;
    const int l31 = lane & 31, hi = lane >> 5;

    __shared__ __align__(16) bf16_t Kst[2][32 * KLD];
    __shared__ __align__(16) bf16_t Vst[2][64 * VLD];
    __shared__ __align__(16) bf16_t tlds[4][32 * 68];
    bf16_t* tw = &tlds[wid][0];

    const bf16_t* Qp = QKV + (size_t)(b * 2048 + qbase + l31) * 1536 + h * 64 + hi * 8;
    const bf16_t* Kbase = QKV + (size_t)(b * 2048) * 1536 + 512 + h * 64;
    const bf16_t* Vbase = Vt + (size_t)bh * 64 * 2048;

    // cooperative staging geometry (16B per thread per tile)
    const int kr = tid >> 3, kc = (tid & 7) * 8;   // K: 8 thr/row, 32 rows
    const int vr = tid >> 2, vc = (tid & 3) * 8;   // V^T: 4 thr/row, 64 rows

    bf16x8 qf[4];
#pragma unroll
    for (int t = 0; t < 4; t++)
        qf[t] = *(const bf16x8*)(Qp + t * 16);

    f32x16 acc0 = {}, acc1 = {};
    float mrun = -1e30f, lsum = 0.f;

    const int kv0 = split * 512;

    // prologue: stage tile 0 into buf 0
    bf16x8 kreg = *(const bf16x8*)(Kbase + (size_t)(kv0 + kr) * 1536 + kc);
    bf16x8 vreg = *(const bf16x8*)(Vbase + (size_t)vr * 2048 + kv0 + vc);
    *(bf16x8*)&Kst[0][kr * KLD + kc] = kreg;
    *(bf16x8*)&Vst[0][vr * VLD + vc] = vreg;
    __syncthreads();

    int buf = 0;
#pragma unroll 2
    for (int kt = kv0; kt < kv0 + 512; kt += 32) {
        const bool nxt = (kt + 32 < kv0 + 512);
        // issue next tile's coalesced loads (latency hides under compute)
        if (nxt) {
            kreg = *(const bf16x8*)(Kbase + (size_t)(kt + 32 + kr) * 1536 + kc);
            vreg = *(const bf16x8*)(Vbase + (size_t)vr * 2048 + kt + 32 + vc);
        }

        // fragments from LDS[buf] (0-conflict padded layout)
        bf16x8 kf[4];
#pragma unroll
        for (int t = 0; t < 4; t++)
            kf[t] = *(const bf16x8*)&Kst[buf][l31 * KLD + hi * 8 + t * 16];
        bf16x8 vf00 = *(const bf16x8*)&Vst[buf][l31 * VLD + hi * 8];
        bf16x8 vf01 = *(const bf16x8*)&Vst[buf][l31 * VLD + 16 + hi * 8];
        bf16x8 vf10 = *(const bf16x8*)&Vst[buf][(32 + l31) * VLD + hi * 8];
        bf16x8 vf11 = *(const bf16x8*)&Vst[buf][(32 + l31) * VLD + 16 + hi * 8];

        f32x16 p = {};
        __builtin_amdgcn_s_setprio(1);
        p = __builtin_amdgcn_mfma_f32_32x32x16_bf16(kf[0], qf[0], p, 0, 0, 0);
        p = __builtin_amdgcn_mfma_f32_32x32x16_bf16(kf[1], qf[1], p, 0, 0, 0);
        p = __builtin_amdgcn_mfma_f32_32x32x16_bf16(kf[2], qf[2], p, 0, 0, 0);
        p = __builtin_amdgcn_mfma_f32_32x32x16_bf16(kf[3], qf[3], p, 0, 0, 0);
        __builtin_amdgcn_s_setprio(0);

        float x0 = fmaxf(p[0], p[8]),  x1 = fmaxf(p[1], p[9]);
        float x2 = fmaxf(p[2], p[10]), x3 = fmaxf(p[3], p[11]);
        float x4 = fmaxf(p[4], p[12]), x5 = fmaxf(p[5], p[13]);
        float x6 = fmaxf(p[6], p[14]), x7 = fmaxf(p[7], p[15]);
        x0 = fmaxf(x0, x4); x1 = fmaxf(x1, x5); x2 = fmaxf(x2, x6); x3 = fmaxf(x3, x7);
        float cm = fmaxf(fmaxf(x0, x1), fmaxf(x2, x3));
        cm = fmaxf(cm, __shfl_xor(cm, 32));

        if (__any(cm > mrun + 12.0f)) {
            float mnew = fmaxf(mrun, cm);
            float fac = __builtin_amdgcn_exp2f(mrun - mnew);
#pragma unroll
            for (int i = 0; i < 16; i++) { acc0[i] *= fac; acc1[i] *= fac; }
            lsum *= fac;
            mrun = mnew;
        }

        float e[16];
#pragma unroll
        for (int i = 0; i < 16; i++) e[i] = __builtin_amdgcn_exp2f(p[i] - mrun);

        float s0 = (e[0] + e[8]) + (e[1] + e[9]);
        float s1 = (e[2] + e[10]) + (e[3] + e[11]);
        float s2 = (e[4] + e[12]) + (e[5] + e[13]);
        float s3 = (e[6] + e[14]) + (e[7] + e[15]);
        float ts = (s0 + s1) + (s2 + s3);
        ts += __shfl_xor(ts, 32);
        lsum += ts;

        u32 pk0 = pkbf(e[0], e[1]),   pk1 = pkbf(e[2], e[3]);
        u32 pk2 = pkbf(e[4], e[5]),   pk3 = pkbf(e[6], e[7]);
        u32 pk4 = pkbf(e[8], e[9]),   pk5 = pkbf(e[10], e[11]);
        u32 pk6 = pkbf(e[12], e[13]), pk7 = pkbf(e[14], e[15]);
        u32 s0w = __shfl_xor(pk0, 32), s1w = __shfl_xor(pk1, 32);
        u32 s2w = __shfl_xor(pk2, 32), s3w = __shfl_xor(pk3, 32);
        u32 s4w = __shfl_xor(pk4, 32), s5w = __shfl_xor(pk5, 32);
        u32 s6w = __shfl_xor(pk6, 32), s7w = __shfl_xor(pk7, 32);

        BU b0, b1;
        b0.d[0] = hi ? s2w : pk0;  b0.d[1] = hi ? s3w : pk1;
        b0.d[2] = hi ? pk2 : s0w;  b0.d[3] = hi ? pk3 : s1w;
        b1.d[0] = hi ? s6w : pk4;  b1.d[1] = hi ? s7w : pk5;
        b1.d[2] = hi ? pk6 : s4w;  b1.d[3] = hi ? pk7 : s5w;

        __builtin_amdgcn_s_setprio(1);
        acc0 = __builtin_amdgcn_mfma_f32_32x32x16_bf16(vf00, b0.v, acc0, 0, 0, 0);
        acc0 = __builtin_amdgcn_mfma_f32_32x32x16_bf16(vf01, b1.v, acc0, 0, 0, 0);
        acc1 = __builtin_amdgcn_mfma_f32_32x32x16_bf16(vf10, b0.v, acc1, 0, 0, 0);
        acc1 = __builtin_amdgcn_mfma_f32_32x32x16_bf16(vf11, b1.v, acc1, 0, 0, 0);
        __builtin_amdgcn_s_setprio(0);

        // commit next tile into buf^1 (after this iter's LDS reads)
        if (nxt) {
            *(bf16x8*)&Kst[buf ^ 1][kr * KLD + kc] = kreg;
            *(bf16x8*)&Vst[buf ^ 1][vr * VLD + vc] = vreg;
        }
        __syncthreads();
        buf ^= 1;
    }

    float inv = 1.f / lsum;
#pragma unroll
    for (int r = 0; r < 16; r++) {
        int drow = (r & 3) + 8 * (r >> 2) + 4 * hi;
        tw[l31 * 68 + drow]      = (bf16_t)(acc0[r] * inv);
        tw[l31 * 68 + 32 + drow] = (bf16_t)(acc1[r] * inv);
    }
    bf16_t* Op = (split < 2) ? Op01 + (size_t)split * SPLIT_ROWS * 64
                             : Op23 + (size_t)(split - 2) * SPLIT_ROWS * 64;
    const size_t rowbase = (size_t)bh * 2048 + qbase;
#pragma unroll
    for (int ps = 0; ps < 4; ps++) {
        int rr = (lane >> 3) + ps * 8;
        int cc = lane & 7;
        bf16x8 ov = *(const bf16x8*)&tw[rr * 68 + cc * 8];
        *(bf16x8*)(Op + (rowbase + rr) * 64 + cc * 8) = ov;
    }
    if (lane < 32)
        ml[(size_t)split * SPLIT_ROWS + rowbase + l31] = make_float2(mrun, lsum);
}

// ---------------- combine 4 KV-split partials -> O f32 [4096][512] ----------------
__global__ __launch_bounds__(256)
void combine_kernel(const bf16_t* __restrict__ Op01, const bf16_t* __restrict__ Op23,
                    const float2* __restrict__ ml, float* __restrict__ O)
{
    int t = blockIdx.x * 256 + threadIdx.x;
    int dim = t & 63;
    int row = t >> 6;                          // bh*2048 + qrow, < 32768
    int bh = row >> 11, qrow = row & 2047;
    float2 m0 = ml[row];
    float2 m1 = ml[SPLIT_ROWS + row];
    float2 m2 = ml[2 * SPLIT_ROWS + row];
    float2 m3 = ml[3 * SPLIT_ROWS + row];
    float M = fmaxf(fmaxf(m0.x, m1.x), fmaxf(m2.x, m3.x));
    float w0 = m0.y * __builtin_amdgcn_exp2f(m0.x - M);
    float w1 = m1.y * __builtin_amdgcn_exp2f(m1.x - M);
    float w2 = m2.y * __builtin_amdgcn_exp2f(m2.x - M);
    float w3 = m3.y * __builtin_amdgcn_exp2f(m3.x - M);
    float o = (w0 * (float)Op01[(size_t)row * 64 + dim]
             + w1 * (float)Op01[(size_t)(SPLIT_ROWS + row) * 64 + dim]
             + w2 * (float)Op23[(size_t)row * 64 + dim]
             + w3 * (float)Op23[(size_t)(SPLIT_ROWS + row) * 64 + dim]) / (w0 + w1 + w2 + w3);
    int b = bh >> 3, h = bh & 7;
    O[((size_t)(b * 2048 + qrow)) * 512 + h * 64 + dim] = o;
}

// ---------------- fused residual-add + LayerNorm (D=512) ----------------
template<bool RESBF>
__global__ __launch_bounds__(128)
void add_ln_kernel(const float* __restrict__ a, const void* __restrict__ res,
                   const float* __restrict__ g, const float* __restrict__ bta,
                   float* outf, bf16_t* outb)
{
    const int row = blockIdx.x, tid = threadIdx.x;
    const float4* a4 = (const float4*)(a + (size_t)row * 512);
    float4 av = a4[tid];
    float r0, r1, r2, r3;
    if (RESBF) {
        bf16x4 rv = ((const bf16x4*)res)[row * 128 + tid];
        r0 = (float)rv[0]; r1 = (float)rv[1]; r2 = (float)rv[2]; r3 = (float)rv[3];
    } else {
        float4 rv = ((const float4*)res)[row * 128 + tid];
        r0 = rv.x; r1 = rv.y; r2 = rv.z; r3 = rv.w;
    }
    float x0 = av.x + r0, x1 = av.y + r1, x2 = av.z + r2, x3 = av.w + r3;
    float s = x0 + x1 + x2 + x3;
    float sq = x0 * x0 + x1 * x1 + x2 * x2 + x3 * x3;
#pragma unroll
    for (int d = 1; d < 64; d <<= 1) { s += __shfl_xor(s, d); sq += __shfl_xor(sq, d); }
    __shared__ float red[2][2];
    const int wid = tid >> 6;
    if ((tid & 63) == 0) { red[wid][0] = s; red[wid][1] = sq; }
    __syncthreads();
    s = red[0][0] + red[1][0];
    sq = red[0][1] + red[1][1];
    float mu = s * (1.f / 512.f);
    float var = sq * (1.f / 512.f) - mu * mu;
    float rstd = rsqrtf(var + 1e-5f);
    const float4* g4 = (const float4*)g;
    const float4* b4 = (const float4*)bta;
    float4 gv = g4[tid], bv = b4[tid];
    float4 y;
    y.x = (x0 - mu) * rstd * gv.x + bv.x;
    y.y = (x1 - mu) * rstd * gv.y + bv.y;
    y.z = (x2 - mu) * rstd * gv.z + bv.z;
    y.w = (x3 - mu) * rstd * gv.w + bv.w;
    if (outf) ((float4*)(outf + (size_t)row * 512))[tid] = y;
    if (outb) {
        bf16x4 o;
        o[0] = (bf16_t)y.x; o[1] = (bf16_t)y.y; o[2] = (bf16_t)y.z; o[3] = (bf16_t)y.w;
        *(bf16x4*)(outb + (size_t)row * 512 + tid * 4) = o;
    }
}

// ---------------- orchestration ----------------
// Workspace arena (29.5 MB high-water; lifetime-safe aliasing) — R8/R10 layout (verified):
//   0- 2 MB : W1t    (A->F)
//   2- 4 MB : W2t    (A->G)
//   4-12 MB : Xb(4-8)+Eb(8-12) (A->B); then Opart splits 0-1 (D->D2); then out1b at 4-8 (E->H)
//  12-24 MB : QKVb   (B->D); then O f32 at 12-20 (D2->E); then Hb 12-28 (F->G)
//  24-28 MB : Vtb    (C->D); then Hb[12:16MB]   (F->G)
//  28-29.5  : Wqkvt  (A->B); then ml 1MB (4x32768 float2) (D->D2)
// d_out: Opart splits 2-3 in first 8 MB (D->D2); then FF f32 (G->H, in-place LN2).
extern "C" void kernel_launch(void* const* d_in, const int* in_sizes, int n_in,
                              void* d_out, int out_size, void* d_ws, size_t ws_size,
                              hipStream_t stream)
{
    const float* inputs = (const float*)d_in[0];
    const float* encx   = (const float*)d_in[1];
    const float* Wq     = (const float*)d_in[2];
    const float* Wk     = (const float*)d_in[3];
    const float* Wv     = (const float*)d_in[4];
    const float* ln1g   = (const float*)d_in[5];
    const float* ln1b   = (const float*)d_in[6];
    const float* W1     = (const float*)d_in[7];
    const float* b1     = (const float*)d_in[8];
    const float* W2     = (const float*)d_in[9];
    const float* b2     = (const float*)d_in[10];
    const float* ln2g   = (const float*)d_in[11];
    const float* ln2b   = (const float*)d_in[12];

    char* ws = (char*)d_ws;
    const size_t MB = 1u << 20;
    bf16_t* W1t   = (bf16_t*)(ws);
    bf16_t* W2t   = (bf16_t*)(ws + 2 * MB);
    bf16_t* Xb    = (bf16_t*)(ws + 4 * MB);
    bf16_t* Op01  = (bf16_t*)(ws + 4 * MB);       // 8 MB, aliases Xb+Eb (dead after QKV gemm)
    bf16_t* out1b = (bf16_t*)(ws + 4 * MB);       // 4 MB, aliases Op01 (dead after combine)
    bf16_t* Eb    = (bf16_t*)(ws + 8 * MB);
    bf16_t* QKVb  = (bf16_t*)(ws + 12 * MB);
    float*  Obuf  = (float*)(ws + 12 * MB);       // 8 MB f32, aliases QKVb (dead after flash)
    bf16_t* Hb    = (bf16_t*)(ws + 12 * MB);      // 16 MB, aliases Obuf+Vtb
    bf16_t* Vtb   = (bf16_t*)(ws + 24 * MB);
    bf16_t* Wqkvt = (bf16_t*)(ws + 28 * MB);
    float2* mlbuf = (float2*)(ws + 28 * MB);      // 1 MB, aliases Wqkvt (dead after QKV gemm)
    bf16_t* Op23  = (bf16_t*)d_out;               // 8 MB, d_out unused until combine
    float*  FF    = (float*)d_out;                // FF (G->H, consumed in-place by ln2)

    // A. merged convert (Q path folds 0.125*log2(e)) + merged weight transposes
    cvt_both_kernel<<<4096, 256, 0, stream>>>(inputs, Xb, 0.125f * 1.44269504f, encx, Eb);
    wtrans_all_kernel<<<2816, 256, 0, stream>>>(Wq, Wk, Wv, W1, W2, Wqkvt, W1t, W2t);
    // B. fused QKV projection: C[4096][1536]
    gemm_kernel<64, true, false, false, true><<<dim3(64, 12), 256, 0, stream>>>(
        Xb, Eb, 4, Wqkvt, nullptr, QKVb, 512, 1536);
    // C. V -> Vt[bh][64][2048]
    vtrans_kernel<<<dim3(32, 16), 256, 0, stream>>>(QKVb, Vtb);
    // D. flash attention (kv-split 4, swapped-QK 32x32, block-shared staging) -> partials
    flash_kernel<<<dim3(16, 16, 4), 256, 0, stream>>>(QKVb, Vtb, Op01, Op23, mlbuf);
    // D2. combine partials -> O f32 [4096][512] (over dead QKVb)
    combine_kernel<<<8192, 256, 0, stream>>>(Op01, Op23, mlbuf, Obuf);
    // E. out1 = LN(O + inputs) -> bf16 only
    add_ln_kernel<false><<<4096, 128, 0, stream>>>(Obuf, inputs, ln1g, ln1b, nullptr, out1b);
    // F. H = relu(out1 @ W1 + b1)  [4096][2048] bf16
    gemm_kernel<128, false, true, true, true><<<dim3(32, 16), 256, 0, stream>>>(
        out1b, nullptr, 0, W1t, b1, Hb, 512, 2048);
    // G. FF = H @ W2 + b2  [4096][512] f32 -> d_out
    gemm_kernel<64, false, true, false, false><<<dim3(64, 4), 256, 0, stream>>>(
        Hb, nullptr, 0, W2t, b2, FF, 2048, 512);
    // H. final = LN(FF + out1b) -> d_out (in-place, row-local)
    add_ln_kernel<true><<<4096, 128, 0, stream>>>(FF, out1b, ln2g, ln2b, (float*)d_out, nullptr);
}

// Round 13
// 135.039 us; speedup vs baseline: 1.5883x; 1.0466x over previous
//
#include <hip/hip_runtime.h>

typedef __bf16 bf16_t;
typedef __bf16 bf16x8 __attribute__((ext_vector_type(8)));
typedef __bf16 bf16x4 __attribute__((ext_vector_type(4)));
typedef float f32x4 __attribute__((ext_vector_type(4)));
typedef float f32x16 __attribute__((ext_vector_type(16)));
typedef unsigned int u32;
typedef unsigned int u32x2 __attribute__((ext_vector_type(2)));

#define GLB_AS(p) ((const __attribute__((address_space(1))) unsigned int*)(p))
#define LDS_AS(p) ((__attribute__((address_space(3))) unsigned int*)(p))

// rows per KV-split = 16 bh * 2048 q = 32768; 4 splits of 512 kv each
#define SPLIT_ROWS 32768
#define KLD 68   // K tile [32 kv][64 d] row stride (pad +4): 0 conflicts (R9-measured)
#define VLD 44   // V^T tile [64 d][32 kv] row stride (pad +12): 0 conflicts (R9-measured)

// ---------------- merged fp32 -> bf16 convert: inputs (scaled) + encoder ----------------
__global__ void cvt_both_kernel(const float* __restrict__ inA, bf16_t* __restrict__ outA, float scaleA,
                                const float* __restrict__ inB, bf16_t* __restrict__ outB)
{
    const int bid = blockIdx.x;
    const float* in;
    bf16_t* out;
    float scale;
    int i;
    if (bid < 2048) { in = inA; out = outA; scale = scaleA; i = (bid * 256 + threadIdx.x) * 4; }
    else            { in = inB; out = outB; scale = 1.0f;  i = ((bid - 2048) * 256 + threadIdx.x) * 4; }
    float4 v = *(const float4*)(in + i);
    bf16x4 o;
    o[0] = (bf16_t)(v.x * scale); o[1] = (bf16_t)(v.y * scale);
    o[2] = (bf16_t)(v.z * scale); o[3] = (bf16_t)(v.w * scale);
    *(bf16x4*)(out + i) = o;
}

// ---------------- merged weight transposes: f32 [R][C] -> bf16 [C][R], 5 jobs ----------------
__global__ void wtrans_all_kernel(const float* __restrict__ Wq, const float* __restrict__ Wk,
                                  const float* __restrict__ Wv, const float* __restrict__ W1,
                                  const float* __restrict__ W2, bf16_t* __restrict__ Wqkvt,
                                  bf16_t* __restrict__ W1t, bf16_t* __restrict__ W2t)
{
    const int j = blockIdx.x;
    const float* in;
    bf16_t* out;
    int R, C, bx, by;
    if (j < 768) {
        int k = j >> 8, l = j & 255;
        in = (k == 0) ? Wq : (k == 1) ? Wk : Wv;
        out = Wqkvt + k * 512 * 512;
        R = 512; C = 512; bx = l & 15; by = l >> 4;
    } else if (j < 1792) {
        int l = j - 768;
        in = W1; out = W1t; R = 512; C = 2048; bx = l % 64; by = l / 64;
    } else {
        int l = j - 1792;
        in = W2; out = W2t; R = 2048; C = 512; bx = l % 16; by = l / 16;
    }
    __shared__ float tile[32][33];
    const int tid = threadIdx.x;
    const int r0 = by * 32, c0 = bx * 32;
#pragma unroll
    for (int t = 0; t < 4; t++) {
        int r = t * 8 + (tid >> 5), c = tid & 31;
        tile[r][c] = in[(size_t)(r0 + r) * C + c0 + c];
    }
    __syncthreads();
#pragma unroll
    for (int t = 0; t < 4; t++) {
        int c = t * 8 + (tid >> 5), r = tid & 31;
        out[(size_t)(c0 + c) * R + r0 + r] = (bf16_t)tile[r][c];
    }
}

// ---------------- V transpose: QKV cols 1024..1535 -> Vt[bh][64][2048] ----------------
__global__ void vtrans_kernel(const bf16_t* __restrict__ qkv, bf16_t* __restrict__ vt)
{
    __shared__ bf16_t t[64][68];
    const int tid = threadIdx.x;
    const int lk0 = blockIdx.x * 64;
    const int bh = blockIdx.y, b = bh >> 3, h = bh & 7;
#pragma unroll
    for (int j = 0; j < 16; j++) {
        int e = j * 256 + tid;
        int lk_i = e >> 6, d = e & 63;
        t[lk_i][d] = qkv[(size_t)(b * 2048 + lk0 + lk_i) * 1536 + 1024 + h * 64 + d];
    }
    __syncthreads();
#pragma unroll
    for (int j = 0; j < 16; j++) {
        int e = j * 256 + tid;
        int d_i = e >> 6, lk = e & 63;
        vt[((size_t)bh * 64 + d_i) * 2048 + lk0 + lk] = t[lk][d_i];
    }
}

// ---------------- GEMM: C[M][N] = A[M][K] @ Bt[N][K]^T ----------------
template<int BM, bool SPLITA, bool BIAS, bool RELU, bool OUTBF16>
__global__ __launch_bounds__(256)
void gemm_kernel(const bf16_t* __restrict__ A0, const bf16_t* __restrict__ A1, int nsplit,
                 const bf16_t* __restrict__ Bt, const float* __restrict__ bias,
                 void* __restrict__ Cout, int K, int ldC)
{
    constexpr int FR = BM / 32;
    __shared__ __align__(16) bf16_t As[BM * 32];
    __shared__ __align__(16) bf16_t Bs[128 * 32];
    const int bm = blockIdx.x, bn = blockIdx.y;
    const bf16_t* A = (!SPLITA || bn < nsplit) ? A0 : A1;
    const int tid = threadIdx.x;
    const int lane = tid & 63;
    const int wid = tid >> 6;
    const int wr = wid >> 1, wc = wid & 1;

    f32x4 acc[FR][4] = {};

    const int cb = wid * 2;
    const int lbB0 = cb * 1024 + lane * 16;
    const int rowB0 = lbB0 >> 6, colB0 = (lbB0 & 63) >> 1;
    const int rowB1 = (lbB0 + 1024) >> 6, colB1 = ((lbB0 + 1024) & 63) >> 1;
    const int lbA0 = (BM == 128 ? cb * 1024 : wid * 1024) + lane * 16;
    const int rowA0 = lbA0 >> 6, colA0 = (lbA0 & 63) >> 1;
    const int rowA1 = (lbA0 + 1024) >> 6, colA1 = ((lbA0 + 1024) & 63) >> 1;

    const bf16_t* Abase = A + (size_t)(bm * BM) * K;
    const bf16_t* Bbase = Bt + (size_t)(bn * 128) * K;

    for (int k0 = 0; k0 < K; k0 += 32) {
        if constexpr (BM == 128) {
            __builtin_amdgcn_global_load_lds(GLB_AS(Abase + (size_t)rowA0 * K + k0 + colA0), LDS_AS(As + cb * 512), 16, 0, 0);
            __builtin_amdgcn_global_load_lds(GLB_AS(Abase + (size_t)rowA1 * K + k0 + colA1), LDS_AS(As + cb * 512 + 512), 16, 0, 0);
        } else {
            __builtin_amdgcn_global_load_lds(GLB_AS(Abase + (size_t)rowA0 * K + k0 + colA0), LDS_AS(As + wid * 512), 16, 0, 0);
        }
        __builtin_amdgcn_global_load_lds(GLB_AS(Bbase + (size_t)rowB0 * K + k0 + colB0), LDS_AS(Bs + cb * 512), 16, 0, 0);
        __builtin_amdgcn_global_load_lds(GLB_AS(Bbase + (size_t)rowB1 * K + k0 + colB1), LDS_AS(Bs + cb * 512 + 512), 16, 0, 0);
        __syncthreads();
        bf16x8 af[FR], bfr[4];
#pragma unroll
        for (int f = 0; f < FR; f++)
            af[f] = *(const bf16x8*)&As[(wr * (BM / 2) + f * 16 + (lane & 15)) * 32 + (lane >> 4) * 8];
#pragma unroll
        for (int f = 0; f < 4; f++)
            bfr[f] = *(const bf16x8*)&Bs[(wc * 64 + f * 16 + (lane & 15)) * 32 + (lane >> 4) * 8];
#pragma unroll
        for (int fr = 0; fr < FR; fr++)
#pragma unroll
            for (int fc = 0; fc < 4; fc++)
                acc[fr][fc] = __builtin_amdgcn_mfma_f32_16x16x32_bf16(af[fr], bfr[fc], acc[fr][fc], 0, 0, 0);
        __syncthreads();
    }

    const int rg = (lane >> 4) * 4, cl = lane & 15;
#pragma unroll
    for (int fc = 0; fc < 4; fc++) {
        const int col = bn * 128 + wc * 64 + fc * 16 + cl;
        float bv = 0.f;
        if (BIAS) bv = bias[col];
#pragma unroll
        for (int fr = 0; fr < FR; fr++) {
#pragma unroll
            for (int r = 0; r < 4; r++) {
                int rowg = bm * BM + wr * (BM / 2) + fr * 16 + rg + r;
                float v = acc[fr][fc][r] + bv;
                if (RELU) v = fmaxf(v, 0.f);
                if (OUTBF16) ((bf16_t*)Cout)[(size_t)rowg * ldC + col] = (bf16_t)v;
                else         ((float*)Cout)[(size_t)rowg * ldC + col] = v;
            }
        }
    }
}

// ---------------- flash attention: swapped-QK^T 32x32, block-shared LDS, permlane softmax ----------------
union BU { bf16x8 v; u32 d[4]; };

static __device__ __forceinline__ u32 pkbf(float a, float b)
{
    union { bf16_t h[2]; u32 w; } u;
    u.h[0] = (bf16_t)a; u.h[1] = (bf16_t)b;
    return u.w;
}

// permlane32_swap: x = {a.lo_lanes, b.lo_lanes}, y = {a.hi_lanes, b.hi_lanes}
static __device__ __forceinline__ void plswap(u32 a, u32 b, u32& x, u32& y)
{
#if __has_builtin(__builtin_amdgcn_permlane32_swap)
    u32x2 r = __builtin_amdgcn_permlane32_swap(a, b, false, false);
    x = r[0]; y = r[1];
#else
    const bool hi = (threadIdx.x & 32) != 0;
    u32 sb = __shfl_xor(b, 32), sa = __shfl_xor(a, 32);
    x = hi ? sb : a;
    y = hi ? b : sa;
#endif
}

// grid (16 qblocks, 16 bh, 4 kv-splits); 4 waves x 32 q-rows = 128 q/block; KVBLK=32.
// Block-shared double-buffered K/V LDS staging (R11, proven). Softmax in-register:
// P = mfma(K,Q) -> p[reg=kv][lane=q]; tile max = 15-fmax tree + permlane32_swap+fmax;
// exp2 domain (Q pre-scaled 0.125*log2 e); T13 defer-rescale; P->bf16 pack + 4 permlane
// swaps assemble both PV B-frags; row-sum accumulated by ones-MFMA (accS) on the matrix
// pipe. O^T = mfma(Vt, P). C-row map: (reg&3)+8*(reg>>2)+4*(lane>>5).
__global__ __launch_bounds__(256)
void flash_kernel(const bf16_t* __restrict__ QKV, const bf16_t* __restrict__ Vt,
                  bf16_t* __restrict__ Op01, bf16_t* __restrict__ Op23,
                  float2* __restrict__ ml)
{
    const int tid = threadIdx.x, lane = tid & 63, wid = tid >> 6;
    const int bh = blockIdx.y, b = bh >> 3, h = bh & 7;
    const int split = blockIdx.z;
    const int qbase = blockIdx.x * 128 + wid * 32;
    const int l31 = lane & 31, hi = lane >> 5;

    __shared__ __align__(16) bf16_t Kst[2][32 * KLD];
    __shared__ __align__(16) bf16_t Vst[2][64 * VLD];
    __shared__ __align__(16) bf16_t tlds[4][32 * 68];
    bf16_t* tw = &tlds[wid][0];

    const bf16_t* Qp = QKV + (size_t)(b * 2048 + qbase + l31) * 1536 + h * 64 + hi * 8;
    const bf16_t* Kbase = QKV + (size_t)(b * 2048) * 1536 + 512 + h * 64;
    const bf16_t* Vbase = Vt + (size_t)bh * 64 * 2048;

    // cooperative staging geometry (16B per thread per tile)
    const int kr = tid >> 3, kc = (tid & 7) * 8;   // K: 8 thr/row, 32 rows
    const int vr = tid >> 2, vc = (tid & 3) * 8;   // V^T: 4 thr/row, 64 rows

    bf16x8 qf[4];
#pragma unroll
    for (int t = 0; t < 4; t++)
        qf[t] = *(const bf16x8*)(Qp + t * 16);

    bf16x8 ones;
#pragma unroll
    for (int e = 0; e < 8; e++) ones[e] = (bf16_t)1.0f;

    f32x16 acc0 = {}, acc1 = {}, accS = {};
    float mrun = -1e30f;

    const int kv0 = split * 512;

    // prologue: stage tile 0 into buf 0
    bf16x8 kreg = *(const bf16x8*)(Kbase + (size_t)(kv0 + kr) * 1536 + kc);
    bf16x8 vreg = *(const bf16x8*)(Vbase + (size_t)vr * 2048 + kv0 + vc);
    *(bf16x8*)&Kst[0][kr * KLD + kc] = kreg;
    *(bf16x8*)&Vst[0][vr * VLD + vc] = vreg;
    __syncthreads();

    int buf = 0;
#pragma unroll 2
    for (int kt = kv0; kt < kv0 + 512; kt += 32) {
        const bool nxt = (kt + 32 < kv0 + 512);
        // issue next tile's coalesced loads (latency hides under compute)
        if (nxt) {
            kreg = *(const bf16x8*)(Kbase + (size_t)(kt + 32 + kr) * 1536 + kc);
            vreg = *(const bf16x8*)(Vbase + (size_t)vr * 2048 + kt + 32 + vc);
        }

        // fragments from LDS[buf] (0-conflict padded layout)
        bf16x8 kf[4];
#pragma unroll
        for (int t = 0; t < 4; t++)
            kf[t] = *(const bf16x8*)&Kst[buf][l31 * KLD + hi * 8 + t * 16];
        bf16x8 vf00 = *(const bf16x8*)&Vst[buf][l31 * VLD + hi * 8];
        bf16x8 vf01 = *(const bf16x8*)&Vst[buf][l31 * VLD + 16 + hi * 8];
        bf16x8 vf10 = *(const bf16x8*)&Vst[buf][(32 + l31) * VLD + hi * 8];
        bf16x8 vf11 = *(const bf16x8*)&Vst[buf][(32 + l31) * VLD + 16 + hi * 8];

        f32x16 p = {};
        __builtin_amdgcn_s_setprio(1);
        p = __builtin_amdgcn_mfma_f32_32x32x16_bf16(kf[0], qf[0], p, 0, 0, 0);
        p = __builtin_amdgcn_mfma_f32_32x32x16_bf16(kf[1], qf[1], p, 0, 0, 0);
        p = __builtin_amdgcn_mfma_f32_32x32x16_bf16(kf[2], qf[2], p, 0, 0, 0);
        p = __builtin_amdgcn_mfma_f32_32x32x16_bf16(kf[3], qf[3], p, 0, 0, 0);
        __builtin_amdgcn_s_setprio(0);

        // tile max: in-register tree + permlane half-exchange
        float x0 = fmaxf(p[0], p[8]),  x1 = fmaxf(p[1], p[9]);
        float x2 = fmaxf(p[2], p[10]), x3 = fmaxf(p[3], p[11]);
        float x4 = fmaxf(p[4], p[12]), x5 = fmaxf(p[5], p[13]);
        float x6 = fmaxf(p[6], p[14]), x7 = fmaxf(p[7], p[15]);
        x0 = fmaxf(x0, x4); x1 = fmaxf(x1, x5); x2 = fmaxf(x2, x6); x3 = fmaxf(x3, x7);
        float cm = fmaxf(fmaxf(x0, x1), fmaxf(x2, x3));
        {
            u32 r0, r1;
            plswap(__float_as_uint(cm), __float_as_uint(cm), r0, r1);
            cm = fmaxf(__uint_as_float(r0), __uint_as_float(r1));
        }

        // T13 defer-rescale
        if (__any(cm > mrun + 12.0f)) {
            float mnew = fmaxf(mrun, cm);
            float fac = __builtin_amdgcn_exp2f(mrun - mnew);
#pragma unroll
            for (int i = 0; i < 16; i++) { acc0[i] *= fac; acc1[i] *= fac; accS[i] *= fac; }
            mrun = mnew;
        }

        float e[16];
#pragma unroll
        for (int i = 0; i < 16; i++) e[i] = __builtin_amdgcn_exp2f(p[i] - mrun);

        // pack to bf16 pairs; permlane half-swaps assemble both PV B-fragments
        u32 pk0 = pkbf(e[0], e[1]),   pk1 = pkbf(e[2], e[3]);
        u32 pk2 = pkbf(e[4], e[5]),   pk3 = pkbf(e[6], e[7]);
        u32 pk4 = pkbf(e[8], e[9]),   pk5 = pkbf(e[10], e[11]);
        u32 pk6 = pkbf(e[12], e[13]), pk7 = pkbf(e[14], e[15]);
        BU b0, b1;
        plswap(pk0, pk2, b0.d[0], b0.d[2]);
        plswap(pk1, pk3, b0.d[1], b0.d[3]);
        plswap(pk4, pk6, b1.d[0], b1.d[2]);
        plswap(pk5, pk7, b1.d[1], b1.d[3]);

        // PV + row-sum (ones-MFMA): O^T[d][q], accS rows all = softmax denominator
        __builtin_amdgcn_s_setprio(1);
        acc0 = __builtin_amdgcn_mfma_f32_32x32x16_bf16(vf00, b0.v, acc0, 0, 0, 0);
        acc0 = __builtin_amdgcn_mfma_f32_32x32x16_bf16(vf01, b1.v, acc0, 0, 0, 0);
        acc1 = __builtin_amdgcn_mfma_f32_32x32x16_bf16(vf10, b0.v, acc1, 0, 0, 0);
        acc1 = __builtin_amdgcn_mfma_f32_32x32x16_bf16(vf11, b1.v, acc1, 0, 0, 0);
        accS = __builtin_amdgcn_mfma_f32_32x32x16_bf16(ones, b0.v, accS, 0, 0, 0);
        accS = __builtin_amdgcn_mfma_f32_32x32x16_bf16(ones, b1.v, accS, 0, 0, 0);
        __builtin_amdgcn_s_setprio(0);

        // commit next tile into buf^1 (after this iter's LDS reads)
        if (nxt) {
            *(bf16x8*)&Kst[buf ^ 1][kr * KLD + kc] = kreg;
            *(bf16x8*)&Vst[buf ^ 1][vr * VLD + vc] = vreg;
        }
        __syncthreads();
        buf ^= 1;
    }

    const float lsum = accS[0];
    float inv = 1.f / lsum;
#pragma unroll
    for (int r = 0; r < 16; r++) {
        int drow = (r & 3) + 8 * (r >> 2) + 4 * hi;
        tw[l31 * 68 + drow]      = (bf16_t)(acc0[r] * inv);
        tw[l31 * 68 + 32 + drow] = (bf16_t)(acc1[r] * inv);
    }
    bf16_t* Op = (split < 2) ? Op01 + (size_t)split * SPLIT_ROWS * 64
                             : Op23 + (size_t)(split - 2) * SPLIT_ROWS * 64;
    const size_t rowbase = (size_t)bh * 2048 + qbase;
#pragma unroll
    for (int ps = 0; ps < 4; ps++) {
        int rr = (lane >> 3) + ps * 8;
        int cc = lane & 7;
        bf16x8 ov = *(const bf16x8*)&tw[rr * 68 + cc * 8];
        *(bf16x8*)(Op + (rowbase + rr) * 64 + cc * 8) = ov;
    }
    if (lane < 32)
        ml[(size_t)split * SPLIT_ROWS + rowbase + l31] = make_float2(mrun, lsum);
}

// ---------------- fused combine(4 splits) + residual-add + LayerNorm -> out1b bf16 ----------------
// grid 4096 rows; 128 threads x 4 dims. m in log2 units.
// NOTE: outb must NOT alias Op01/Op23 (R12 bug: cross-block read/write race).
__global__ __launch_bounds__(128)
void combine_ln_kernel(const bf16_t* __restrict__ Op01, const bf16_t* __restrict__ Op23,
                       const float2* __restrict__ ml, const float* __restrict__ resid,
                       const float* __restrict__ g, const float* __restrict__ bta,
                       bf16_t* __restrict__ outb)
{
    const int row = blockIdx.x;            // b*2048 + q
    const int tid = threadIdx.x;
    const int b = row >> 11, q = row & 2047;
    const int d = tid * 4, h = d >> 6, dd = d & 63;
    const size_t prow = ((size_t)(b * 8 + h)) * 2048 + q;

    float2 m0 = ml[prow];
    float2 m1 = ml[SPLIT_ROWS + prow];
    float2 m2 = ml[2 * SPLIT_ROWS + prow];
    float2 m3 = ml[3 * SPLIT_ROWS + prow];
    float M = fmaxf(fmaxf(m0.x, m1.x), fmaxf(m2.x, m3.x));
    float w0 = m0.y * __builtin_amdgcn_exp2f(m0.x - M);
    float w1 = m1.y * __builtin_amdgcn_exp2f(m1.x - M);
    float w2 = m2.y * __builtin_amdgcn_exp2f(m2.x - M);
    float w3 = m3.y * __builtin_amdgcn_exp2f(m3.x - M);
    float winv = 1.f / (w0 + w1 + w2 + w3);

    bf16x4 p0 = *(const bf16x4*)(Op01 + prow * 64 + dd);
    bf16x4 p1 = *(const bf16x4*)(Op01 + (SPLIT_ROWS + prow) * 64 + dd);
    bf16x4 p2 = *(const bf16x4*)(Op23 + prow * 64 + dd);
    bf16x4 p3 = *(const bf16x4*)(Op23 + (SPLIT_ROWS + prow) * 64 + dd);
    float4 rv = ((const float4*)resid)[row * 128 + tid];

    float x0 = (w0 * (float)p0[0] + w1 * (float)p1[0] + w2 * (float)p2[0] + w3 * (float)p3[0]) * winv + rv.x;
    float x1 = (w0 * (float)p0[1] + w1 * (float)p1[1] + w2 * (float)p2[1] + w3 * (float)p3[1]) * winv + rv.y;
    float x2 = (w0 * (float)p0[2] + w1 * (float)p1[2] + w2 * (float)p2[2] + w3 * (float)p3[2]) * winv + rv.z;
    float x3 = (w0 * (float)p0[3] + w1 * (float)p1[3] + w2 * (float)p2[3] + w3 * (float)p3[3]) * winv + rv.w;

    float s = x0 + x1 + x2 + x3;
    float sq = x0 * x0 + x1 * x1 + x2 * x2 + x3 * x3;
#pragma unroll
    for (int dl = 1; dl < 64; dl <<= 1) { s += __shfl_xor(s, dl); sq += __shfl_xor(sq, dl); }
    __shared__ float red[2][2];
    const int wid = tid >> 6;
    if ((tid & 63) == 0) { red[wid][0] = s; red[wid][1] = sq; }
    __syncthreads();
    s = red[0][0] + red[1][0];
    sq = red[0][1] + red[1][1];
    float mu = s * (1.f / 512.f);
    float var = sq * (1.f / 512.f) - mu * mu;
    float rstd = rsqrtf(var + 1e-5f);
    const float4 gv = ((const float4*)g)[tid];
    const float4 bv = ((const float4*)bta)[tid];
    bf16x4 o;
    o[0] = (bf16_t)((x0 - mu) * rstd * gv.x + bv.x);
    o[1] = (bf16_t)((x1 - mu) * rstd * gv.y + bv.y);
    o[2] = (bf16_t)((x2 - mu) * rstd * gv.z + bv.z);
    o[3] = (bf16_t)((x3 - mu) * rstd * gv.w + bv.w);
    *(bf16x4*)(outb + (size_t)row * 512 + tid * 4) = o;
}

// ---------------- fused residual-add + LayerNorm (D=512) ----------------
template<bool RESBF>
__global__ __launch_bounds__(128)
void add_ln_kernel(const float* __restrict__ a, const void* __restrict__ res,
                   const float* __restrict__ g, const float* __restrict__ bta,
                   float* outf, bf16_t* outb)
{
    const int row = blockIdx.x, tid = threadIdx.x;
    const float4* a4 = (const float4*)(a + (size_t)row * 512);
    float4 av = a4[tid];
    float r0, r1, r2, r3;
    if (RESBF) {
        bf16x4 rv = ((const bf16x4*)res)[row * 128 + tid];
        r0 = (float)rv[0]; r1 = (float)rv[1]; r2 = (float)rv[2]; r3 = (float)rv[3];
    } else {
        float4 rv = ((const float4*)res)[row * 128 + tid];
        r0 = rv.x; r1 = rv.y; r2 = rv.z; r3 = rv.w;
    }
    float x0 = av.x + r0, x1 = av.y + r1, x2 = av.z + r2, x3 = av.w + r3;
    float s = x0 + x1 + x2 + x3;
    float sq = x0 * x0 + x1 * x1 + x2 * x2 + x3 * x3;
#pragma unroll
    for (int d = 1; d < 64; d <<= 1) { s += __shfl_xor(s, d); sq += __shfl_xor(sq, d); }
    __shared__ float red[2][2];
    const int wid = tid >> 6;
    if ((tid & 63) == 0) { red[wid][0] = s; red[wid][1] = sq; }
    __syncthreads();
    s = red[0][0] + red[1][0];
    sq = red[0][1] + red[1][1];
    float mu = s * (1.f / 512.f);
    float var = sq * (1.f / 512.f) - mu * mu;
    float rstd = rsqrtf(var + 1e-5f);
    const float4* g4 = (const float4*)g;
    const float4* b4 = (const float4*)bta;
    float4 gv = g4[tid], bv = b4[tid];
    float4 y;
    y.x = (x0 - mu) * rstd * gv.x + bv.x;
    y.y = (x1 - mu) * rstd * gv.y + bv.y;
    y.z = (x2 - mu) * rstd * gv.z + bv.z;
    y.w = (x3 - mu) * rstd * gv.w + bv.w;
    if (outf) ((float4*)(outf + (size_t)row * 512))[tid] = y;
    if (outb) {
        bf16x4 o;
        o[0] = (bf16_t)y.x; o[1] = (bf16_t)y.y; o[2] = (bf16_t)y.z; o[3] = (bf16_t)y.w;
        *(bf16x4*)(outb + (size_t)row * 512 + tid * 4) = o;
    }
}

// ---------------- orchestration ----------------
// Workspace arena (29.5 MB high-water; lifetime-safe aliasing) — R13 fixed layout:
//   0- 2 MB : W1t    (A->F)
//   2- 4 MB : W2t    (A->G)
//   4-12 MB : Xb(4-8)+Eb(8-12) (A->B); then Op01 splits 0-1 (D->E); then Hb[0:8MB] (F->G)
//  12-24 MB : QKVb   (B->D); then Hb[8:16MB] at 12-20 (F->G); 20-24 free
//  24-28 MB : Vtb    (C->D); then out1b (E->H)   <-- disjoint from Op01 (R12 bug fix)
//  28-29.5  : Wqkvt  (A->B); then ml 1MB (4x32768 float2) (D->E)
// d_out: Op23 splits 2-3 (D->E); then FF f32 (G->H, in-place LN2).
extern "C" void kernel_launch(void* const* d_in, const int* in_sizes, int n_in,
                              void* d_out, int out_size, void* d_ws, size_t ws_size,
                              hipStream_t stream)
{
    const float* inputs = (const float*)d_in[0];
    const float* encx   = (const float*)d_in[1];
    const float* Wq     = (const float*)d_in[2];
    const float* Wk     = (const float*)d_in[3];
    const float* Wv     = (const float*)d_in[4];
    const float* ln1g   = (const float*)d_in[5];
    const float* ln1b   = (const float*)d_in[6];
    const float* W1     = (const float*)d_in[7];
    const float* b1     = (const float*)d_in[8];
    const float* W2     = (const float*)d_in[9];
    const float* b2     = (const float*)d_in[10];
    const float* ln2g   = (const float*)d_in[11];
    const float* ln2b   = (const float*)d_in[12];

    char* ws = (char*)d_ws;
    const size_t MB = 1u << 20;
    bf16_t* W1t   = (bf16_t*)(ws);
    bf16_t* W2t   = (bf16_t*)(ws + 2 * MB);
    bf16_t* Xb    = (bf16_t*)(ws + 4 * MB);
    bf16_t* Op01  = (bf16_t*)(ws + 4 * MB);       // 8 MB, aliases Xb+Eb (dead after QKV gemm)
    bf16_t* Hb    = (bf16_t*)(ws + 4 * MB);       // 16 MB @4-20, aliases Op01(dead after E)+QKVb
    bf16_t* Eb    = (bf16_t*)(ws + 8 * MB);
    bf16_t* QKVb  = (bf16_t*)(ws + 12 * MB);
    bf16_t* Vtb   = (bf16_t*)(ws + 24 * MB);
    bf16_t* out1b = (bf16_t*)(ws + 24 * MB);      // 4 MB, aliases Vtb (dead after flash)
    bf16_t* Wqkvt = (bf16_t*)(ws + 28 * MB);
    float2* mlbuf = (float2*)(ws + 28 * MB);      // 1 MB, aliases Wqkvt (dead after QKV gemm)
    bf16_t* Op23  = (bf16_t*)d_out;               // 8 MB, d_out unused until combine_ln
    float*  FF    = (float*)d_out;                // FF (G->H, consumed in-place by ln2)

    // A. merged convert (Q path folds 0.125*log2(e)) + merged weight transposes
    cvt_both_kernel<<<4096, 256, 0, stream>>>(inputs, Xb, 0.125f * 1.44269504f, encx, Eb);
    wtrans_all_kernel<<<2816, 256, 0, stream>>>(Wq, Wk, Wv, W1, W2, Wqkvt, W1t, W2t);
    // B. fused QKV projection: C[4096][1536]
    gemm_kernel<64, true, false, false, true><<<dim3(64, 12), 256, 0, stream>>>(
        Xb, Eb, 4, Wqkvt, nullptr, QKVb, 512, 1536);
    // C. V -> Vt[bh][64][2048]
    vtrans_kernel<<<dim3(32, 16), 256, 0, stream>>>(QKVb, Vtb);
    // D. flash attention (kv-split 4, swapped-QK 32x32, block-shared staging) -> partials
    flash_kernel<<<dim3(16, 16, 4), 256, 0, stream>>>(QKVb, Vtb, Op01, Op23, mlbuf);
    // E. fused combine + LN1: out1 = LN(O + inputs) -> bf16 at 24-28 MB (no alias with Op01/Op23)
    combine_ln_kernel<<<4096, 128, 0, stream>>>(Op01, Op23, mlbuf, inputs, ln1g, ln1b, out1b);
    // F. H = relu(out1 @ W1 + b1)  [4096][2048] bf16 -> 4-20 MB
    gemm_kernel<128, false, true, true, true><<<dim3(32, 16), 256, 0, stream>>>(
        out1b, nullptr, 0, W1t, b1, Hb, 512, 2048);
    // G. FF = H @ W2 + b2  [4096][512] f32 -> d_out
    gemm_kernel<64, false, true, false, false><<<dim3(64, 4), 256, 0, stream>>>(
        Hb, nullptr, 0, W2t, b2, FF, 2048, 512);
    // H. final = LN(FF + out1b) -> d_out (in-place, row-local)
    add_ln_kernel<true><<<4096, 128, 0, stream>>>(FF, out1b, ln2g, ln2b, (float*)d_out, nullptr);
}